// Round 9
// baseline (388.035 us; speedup 1.0000x reference)
//
#include <hip/hip_runtime.h>

#define NN   50000
#define FIN  256
#define HD   128
#define CC   64
#define KK   4
#define RWSS 16
#define NRW  (NN*RWSS)          // 800000
#define KNRW (KK*NRW)           // 3200000

typedef unsigned int   uint32;
typedef unsigned short ushort_t;

typedef __attribute__((ext_vector_type(8))) short short8v;   // 8 bf16
typedef __attribute__((ext_vector_type(4))) float float4v;   // MFMA acc
typedef __attribute__((ext_vector_type(4))) uint32 uint4v;   // native 16B vec

static __device__ __forceinline__ float bf16lo(uint32 u) {
    return __uint_as_float(u << 16);
}
static __device__ __forceinline__ float bf16hi(uint32 u) {
    return __uint_as_float(u & 0xFFFF0000u);
}
static __device__ __forceinline__ ushort_t f2bf16(float f) {
    uint32 u = __float_as_uint(f);
    uint32 r = u + 0x7FFFu + ((u >> 16) & 1u);   // RNE
    return (ushort_t)(r >> 16);
}

// ---------------------------------------------------------------------------
// One-time weight conversion fp32 -> bf16 k-major 16B chunks [k8][col].
// ---------------------------------------------------------------------------
static __device__ __forceinline__ uint4 packw(const float* p) {
    const float4 w0 = *(const float4*)p;
    const float4 w1 = *(const float4*)(p + 4);
    uint4 q;
    q.x = (uint32)f2bf16(w0.x) | ((uint32)f2bf16(w0.y) << 16);
    q.y = (uint32)f2bf16(w0.z) | ((uint32)f2bf16(w0.w) << 16);
    q.z = (uint32)f2bf16(w1.x) | ((uint32)f2bf16(w1.y) << 16);
    q.w = (uint32)f2bf16(w1.z) | ((uint32)f2bf16(w1.w) << 16);
    return q;
}

__global__ __launch_bounds__(256) void prep_w_kernel(
    const float* __restrict__ w0, const float* __restrict__ w1,
    const float* __restrict__ wo,
    uint4* __restrict__ t0, uint4* __restrict__ t1, uint4* __restrict__ to_)
{
    const int idx = blockIdx.x * 256 + threadIdx.x;
    if (idx < 4096) {                       // lin0: [k8][j], j<128, k8<32
        const int jj = idx & 127, k8 = idx >> 7;
        t0[idx] = packw(w0 + (size_t)jj * FIN + 8 * k8);
    } else if (idx < 6144) {                // lin1: [k8][j], j<128, k8<16
        const int li = idx - 4096;
        const int jj = li & 127, k8 = li >> 7;
        t1[li] = packw(w1 + (size_t)jj * HD + 8 * k8);
    } else if (idx < 7168) {                // lout: [k8][c], c<64, k8<16
        const int li = idx - 6144;
        const int jj = li & 63, k8 = li >> 6;
        to_[li] = packw(wo + (size_t)jj * HD + 8 * k8);
    }
}

// ---------------------------------------------------------------------------
// MFMA linear + fused attention projections. B-fragments straight from the
// bf16 W table. Block = 4 waves; wave owns 16 rows x 128 cols.
// Output h16s is SLICE-MAJOR: [slice s][node][32 ch], s = ch>>5.
// ---------------------------------------------------------------------------
template<int DIN, bool ABF16>
__global__ __launch_bounds__(256) void linear_mfma_kernel(
    const void* __restrict__ Ain, const uint4* __restrict__ W16,
    const float* __restrict__ bias,
    const float* __restrict__ alw, const float* __restrict__ alb,
    const float* __restrict__ arw, const float* __restrict__ arb,
    ushort_t* __restrict__ h16s, float* __restrict__ al, float* __restrict__ ar)
{
    const int tid  = threadIdx.x;
    const int wid  = tid >> 6;
    const int lane = tid & 63;
    const int mrow = lane & 15;
    const int kq   = lane >> 4;
    const int row  = blockIdx.x * 64 + wid * 16 + mrow;
    const int arow = row < NN ? row : NN - 1;

    float4v acc[8];
#pragma unroll
    for (int t = 0; t < 8; ++t) acc[t] = (float4v){0.f, 0.f, 0.f, 0.f};

    for (int f0 = 0; f0 < DIN; f0 += 32) {
        short8v a;
        if constexpr (ABF16) {
            a = *(const short8v*)((const ushort_t*)Ain + (size_t)arow * DIN + f0 + 8 * kq);
        } else {
            const float* ap = (const float*)Ain + (size_t)arow * DIN + f0 + 8 * kq;
            const float4 a0 = *(const float4*)ap;
            const float4 a1 = *(const float4*)(ap + 4);
            a[0] = (short)f2bf16(a0.x); a[1] = (short)f2bf16(a0.y);
            a[2] = (short)f2bf16(a0.z); a[3] = (short)f2bf16(a0.w);
            a[4] = (short)f2bf16(a1.x); a[5] = (short)f2bf16(a1.y);
            a[6] = (short)f2bf16(a1.z); a[7] = (short)f2bf16(a1.w);
        }
        const int k8 = (f0 >> 3) + kq;
#pragma unroll
        for (int t = 0; t < 8; ++t) {
            const short8v b = ((const short8v*)W16)[(k8 << 7) + 16 * t + mrow];
            acc[t] = __builtin_amdgcn_mfma_f32_16x16x32_bf16(a, b, acc[t], 0, 0, 0);
        }
    }

    // ---- epilogue: bias, slice-major bf16 store, fused al/ar ----
    float pa[4] = {0.f, 0.f, 0.f, 0.f};
    float pr[4] = {0.f, 0.f, 0.f, 0.f};
    float hb[8][4];
#pragma unroll
    for (int t = 0; t < 8; ++t) {
        const float bj = bias[16 * t + mrow];
        const float wl = alw[16 * t + mrow];
        const float wr = arw[16 * t + mrow];
#pragma unroll
        for (int g = 0; g < 4; ++g) {
            const float h = acc[t][g] + bj;
            hb[t][g] = h;
            pa[g] = fmaf(h, wl, pa[g]);
            pr[g] = fmaf(h, wr, pr[g]);
        }
    }
    const int rbase = blockIdx.x * 64 + wid * 16 + 4 * kq;
#pragma unroll
    for (int g = 0; g < 4; ++g) {
        const int orow = rbase + g;
        if (orow < NN) {
#pragma unroll
            for (int t = 0; t < 8; ++t) {
                // channel c = 16t + mrow; slice = t>>1; offset = 16*(t&1)+mrow
                h16s[(size_t)(t >> 1) * (NN * 32) + (size_t)orow * 32 +
                     16 * (t & 1) + mrow] = f2bf16(hb[t][g]);
            }
        }
    }
#pragma unroll
    for (int o = 8; o >= 1; o >>= 1) {
#pragma unroll
        for (int g = 0; g < 4; ++g) {
            pa[g] += __shfl_xor(pa[g], o, 16);
            pr[g] += __shfl_xor(pr[g], o, 16);
        }
    }
    if (mrow == 0) {
#pragma unroll
        for (int g = 0; g < 4; ++g) {
            const int orow = rbase + g;
            if (orow < NN) {
                al[orow] = pa[g] + alb[0];
                ar[orow] = pr[g] + arb[0];
            }
        }
    }
}

// ---------------------------------------------------------------------------
// Pair prep: packed (w_bf16 << 16 | e) per (node, k, j). One wave per node.
// ---------------------------------------------------------------------------
__global__ __launch_bounds__(256) void prep_pairs_kernel(
    const int* __restrict__ ends_l, const float* __restrict__ al,
    const float* __restrict__ ar, const float* __restrict__ att_l,
    uint32* __restrict__ pw)
{
    const int wv   = threadIdx.x >> 6;
    const int lane = threadIdx.x & 63;
    const int node = blockIdx.x * 4 + wv;
    const int k    = lane >> 4;
    const int j    = lane & 15;

    const int e = __builtin_nontemporal_load(ends_l + (size_t)k * NRW + node * RWSS + j);
    float lg = al[node] + ar[e];
    lg = (lg > 0.f) ? lg : 0.2f * lg;
    float m = lg;
#pragma unroll
    for (int o = 8; o >= 1; o >>= 1) m = fmaxf(m, __shfl_xor(m, o, 16));
    const float ex = __expf(lg - m);
    float s = ex;
#pragma unroll
    for (int o = 8; o >= 1; o >>= 1) s += __shfl_xor(s, o, 16);
    const float w = ex / s * att_l[k + 1] * (1.0f / RWSS);
    const uint32 packed = ((uint32)f2bf16(w) << 16) | (uint32)e;   // e < 65536
    __builtin_nontemporal_store(packed, pw + (size_t)node * 64 + lane);
}

// ---------------------------------------------------------------------------
// Aggregation v4: ONE dispatch per layer; slice pinned to an XCD pair via
// bid&7 (each XCD's L2 permanently holds one 3.2 MB channel-slice).
// Block = 256 = 4 waves = 16 nodes. Wave = 4 nodes; lane = g*16 + r*4 + q.
// Inner loop in TWO BATCHES OF 8: issue 8 independent dwordx4 gathers into
// named regs (static unroll -> registers), then 64 fmas. ~60 VGPR live ->
// fits the 64-VGPR / 8-waves-per-SIMD cliff; in-flight loads per SIMD ~64.
// ---------------------------------------------------------------------------
__global__ __launch_bounds__(256, 8) void aggr_slice_kernel(
    const ushort_t* __restrict__ h16s, const uint32* __restrict__ pw,
    const float* __restrict__ att_l, ushort_t* __restrict__ agg16)
{
    const int bid = blockIdx.x;
    const int xcd = bid & 7;
    const int s   = xcd >> 1;                       // slice 0..3
    const int ng  = (bid >> 3) + (xcd & 1) * 1563;  // node-group within slice
    if (ng >= 3125) return;                         // block-uniform guard
    const int node0 = ng * 16;

    __shared__ uint32 pair_s[16 * 68];
    const int tid = threadIdx.x;
    // stage 1024 pairs (16 nodes x 64), NT dwordx4, stride-68 LDS rows
    {
        const uint4v p4 = __builtin_nontemporal_load(
            (const uint4v*)(pw + (size_t)node0 * 64) + tid);
        const int nl = tid >> 4;
        const int sm = (4 * tid) & 63;
        *(uint4v*)&pair_s[nl * 68 + sm] = p4;
    }
    __syncthreads();

    const int lane = tid & 63;
    const int w    = tid >> 6;
    const int g    = lane >> 4;
    const int r    = (lane >> 2) & 3;
    const int q    = lane & 3;
    const int nl   = w * 4 + g;
    const uint32 qb = (uint32)(q << 4);
    const char* hbase = (const char*)(h16s + (size_t)s * (NN * 32));
    const uint32* ps = &pair_s[nl * 68 + r];

    float acc[8];
#pragma unroll
    for (int c = 0; c < 8; ++c) acc[c] = 0.f;

#pragma unroll
    for (int half = 0; half < 2; ++half) {
        uint32 wgt[8];
        uint4v vv[8];
#pragma unroll
        for (int i = 0; i < 8; ++i) {
            const uint32 p = ps[4 * (8 * half + i)];   // imm-offset ds_read
            wgt[i] = p & 0xFFFF0000u;
            vv[i]  = *(const uint4v*)(hbase + (((p & 0xFFFFu) << 6) + qb));
        }
#pragma unroll
        for (int i = 0; i < 8; ++i) {
            const float w8 = __uint_as_float(wgt[i]);
            acc[0] = fmaf(bf16lo(vv[i].x), w8, acc[0]);
            acc[1] = fmaf(bf16hi(vv[i].x), w8, acc[1]);
            acc[2] = fmaf(bf16lo(vv[i].y), w8, acc[2]);
            acc[3] = fmaf(bf16hi(vv[i].y), w8, acc[3]);
            acc[4] = fmaf(bf16lo(vv[i].z), w8, acc[4]);
            acc[5] = fmaf(bf16hi(vv[i].z), w8, acc[5]);
            acc[6] = fmaf(bf16lo(vv[i].w), w8, acc[6]);
            acc[7] = fmaf(bf16hi(vv[i].w), w8, acc[7]);
        }
    }

#pragma unroll
    for (int c = 0; c < 8; ++c) {
        acc[c] += __shfl_xor(acc[c], 4, 16);
        acc[c] += __shfl_xor(acc[c], 8, 16);
    }

    if (r == 0) {
        const int node = node0 + nl;
        const uint4v v = *(const uint4v*)(hbase + (((uint32)node << 6) + qb));
        const float a0 = att_l[0];
        acc[0] = fmaf(bf16lo(v.x), a0, acc[0]);
        acc[1] = fmaf(bf16hi(v.x), a0, acc[1]);
        acc[2] = fmaf(bf16lo(v.y), a0, acc[2]);
        acc[3] = fmaf(bf16hi(v.y), a0, acc[3]);
        acc[4] = fmaf(bf16lo(v.z), a0, acc[4]);
        acc[5] = fmaf(bf16hi(v.z), a0, acc[5]);
        acc[6] = fmaf(bf16lo(v.w), a0, acc[6]);
        acc[7] = fmaf(bf16hi(v.w), a0, acc[7]);
        uint4v o;
        o.x = (uint32)f2bf16(acc[0]) | ((uint32)f2bf16(acc[1]) << 16);
        o.y = (uint32)f2bf16(acc[2]) | ((uint32)f2bf16(acc[3]) << 16);
        o.z = (uint32)f2bf16(acc[4]) | ((uint32)f2bf16(acc[5]) << 16);
        o.w = (uint32)f2bf16(acc[6]) | ((uint32)f2bf16(acc[7]) << 16);
        __builtin_nontemporal_store(
            o, (uint4v*)((char*)agg16 + (size_t)node * 256 + s * 64 + qb));
    }
}

// ---------------------------------------------------------------------------
// Output head: MFMA GEMM (h @ lout_w^T + b) + fused log_softmax.
// ---------------------------------------------------------------------------
__global__ __launch_bounds__(256) void out_mfma_kernel(
    const ushort_t* __restrict__ agg16, const uint4* __restrict__ WO16,
    const float* __restrict__ lb, float* __restrict__ outp)
{
    const int tid  = threadIdx.x;
    const int wid  = tid >> 6;
    const int lane = tid & 63;
    const int mrow = lane & 15;
    const int kq   = lane >> 4;
    const int row  = blockIdx.x * 64 + wid * 16 + mrow;
    const int arow = row < NN ? row : NN - 1;

    float4v acc[4];
#pragma unroll
    for (int t = 0; t < 4; ++t) acc[t] = (float4v){0.f, 0.f, 0.f, 0.f};

#pragma unroll
    for (int f0 = 0; f0 < HD; f0 += 32) {
        const short8v a = *(const short8v*)(agg16 + (size_t)arow * HD + f0 + 8 * kq);
        const int k8 = (f0 >> 3) + kq;
#pragma unroll
        for (int t = 0; t < 4; ++t) {
            const short8v b = ((const short8v*)WO16)[(k8 << 6) + 16 * t + mrow];
            acc[t] = __builtin_amdgcn_mfma_f32_16x16x32_bf16(a, b, acc[t], 0, 0, 0);
        }
    }

    float v[4][4];
    float mx[4] = {-1e30f, -1e30f, -1e30f, -1e30f};
#pragma unroll
    for (int t = 0; t < 4; ++t) {
        const float bj = lb[16 * t + mrow];
#pragma unroll
        for (int g = 0; g < 4; ++g) {
            v[t][g] = acc[t][g] + bj;
            mx[g] = fmaxf(mx[g], v[t][g]);
        }
    }
#pragma unroll
    for (int o = 8; o >= 1; o >>= 1)
#pragma unroll
        for (int g = 0; g < 4; ++g) mx[g] = fmaxf(mx[g], __shfl_xor(mx[g], o, 16));
    float sm[4] = {0.f, 0.f, 0.f, 0.f};
#pragma unroll
    for (int t = 0; t < 4; ++t)
#pragma unroll
        for (int g = 0; g < 4; ++g) sm[g] += __expf(v[t][g] - mx[g]);
#pragma unroll
    for (int o = 8; o >= 1; o >>= 1)
#pragma unroll
        for (int g = 0; g < 4; ++g) sm[g] += __shfl_xor(sm[g], o, 16);
    float lgs[4];
#pragma unroll
    for (int g = 0; g < 4; ++g) lgs[g] = __logf(sm[g]);

    const int rbase = blockIdx.x * 64 + wid * 16 + 4 * kq;
#pragma unroll
    for (int g = 0; g < 4; ++g) {
        const int orow = rbase + g;
        if (orow < NN) {
#pragma unroll
            for (int t = 0; t < 4; ++t)
                outp[(size_t)orow * CC + 16 * t + mrow] = v[t][g] - mx[g] - lgs[g];
        }
    }
}

// ---------------------------------------------------------------------------
extern "C" void kernel_launch(void* const* d_in, const int* in_sizes, int n_in,
                              void* d_out, int out_size, void* d_ws, size_t ws_size,
                              hipStream_t stream)
{
    const float* x      = (const float*)d_in[0];
    const int*   ends   = (const int*)  d_in[1];
    const float* lin0_w = (const float*)d_in[2];
    const float* lin0_b = (const float*)d_in[3];
    const float* lin1_w = (const float*)d_in[4];
    const float* lin1_b = (const float*)d_in[5];
    const float* lout_w = (const float*)d_in[6];
    const float* lout_b = (const float*)d_in[7];
    const float* attl_w = (const float*)d_in[8];
    const float* attl_b = (const float*)d_in[9];
    const float* attr_w = (const float*)d_in[10];
    const float* attr_b = (const float*)d_in[11];
    const float* att    = (const float*)d_in[12];
    float* outp = (float*)d_out;

    // workspace layout (~39 MB)
    ushort_t* h16s  = (ushort_t*)d_ws;                    // slice-major table, 12.8MB
    ushort_t* agg16 = h16s + (size_t)NN * HD;             // row-major agg, 12.8MB
    float*    albuf = (float*)(agg16 + (size_t)NN * HD);  // 50000
    float*    arbuf = albuf + NN;                         // 50000
    uint32*   pw    = (uint32*)(arbuf + NN);              // 3.2M packed pairs, 12.8MB
    uint4*    t0    = (uint4*)(pw + (size_t)KNRW);        // 4096 chunks
    uint4*    t1    = t0 + 4096;                          // 2048 chunks
    uint4*    to_   = t1 + 2048;                          // 1024 chunks

    const int lin_grid  = (NN + 63) / 64;   // 782
    const int nb4       = NN / 4;           // 12500, exact
    const int aggr_grid = 8 * 1563;         // 12504 (xcd-pinned slices)

    prep_w_kernel<<<28, 256, 0, stream>>>(lin0_w, lin1_w, lout_w, t0, t1, to_);

    // ---- layer 0 ----
    linear_mfma_kernel<FIN, false><<<lin_grid, 256, 0, stream>>>(
        x, t0, lin0_b, attl_w, attl_b, attr_w, attr_b, h16s, albuf, arbuf);
    prep_pairs_kernel<<<nb4, 256, 0, stream>>>(ends, albuf, arbuf, att, pw);
    aggr_slice_kernel<<<aggr_grid, 256, 0, stream>>>(h16s, pw, att, agg16);

    // ---- layer 1 ----
    linear_mfma_kernel<HD, true><<<lin_grid, 256, 0, stream>>>(
        agg16, t1, lin1_b, attl_w + HD, attl_b + 1, attr_w + HD, attr_b + 1,
        h16s, albuf, arbuf);
    prep_pairs_kernel<<<nb4, 256, 0, stream>>>(ends + KNRW, albuf, arbuf,
                                               att + (KK + 1), pw);
    aggr_slice_kernel<<<aggr_grid, 256, 0, stream>>>(h16s, pw, att + (KK + 1), agg16);

    // ---- output head ----
    out_mfma_kernel<<<lin_grid, 256, 0, stream>>>(agg16, to_, lout_b, outp);
}

// Round 10
// 225.278 us; speedup vs baseline: 1.7225x; 1.7225x over previous
//
#include <hip/hip_runtime.h>

#define NN   50000
#define FIN  256
#define HD   128
#define CC   64
#define KK   4
#define RWSS 16
#define NRW  (NN*RWSS)          // 800000
#define KNRW (KK*NRW)           // 3200000

typedef unsigned int   uint32;
typedef unsigned short ushort_t;

typedef __attribute__((ext_vector_type(8))) short short8v;   // 8 bf16
typedef __attribute__((ext_vector_type(4))) float float4v;   // MFMA acc
typedef __attribute__((ext_vector_type(4))) uint32 uint4v;   // native 16B vec

static __device__ __forceinline__ float bf16lo(uint32 u) {
    return __uint_as_float(u << 16);
}
static __device__ __forceinline__ float bf16hi(uint32 u) {
    return __uint_as_float(u & 0xFFFF0000u);
}
static __device__ __forceinline__ ushort_t f2bf16(float f) {
    uint32 u = __float_as_uint(f);
    uint32 r = u + 0x7FFFu + ((u >> 16) & 1u);   // RNE
    return (ushort_t)(r >> 16);
}

// ---------------------------------------------------------------------------
// One-time weight conversion fp32 -> bf16 k-major 16B chunks [k8][col].
// ---------------------------------------------------------------------------
static __device__ __forceinline__ uint4 packw(const float* p) {
    const float4 w0 = *(const float4*)p;
    const float4 w1 = *(const float4*)(p + 4);
    uint4 q;
    q.x = (uint32)f2bf16(w0.x) | ((uint32)f2bf16(w0.y) << 16);
    q.y = (uint32)f2bf16(w0.z) | ((uint32)f2bf16(w0.w) << 16);
    q.z = (uint32)f2bf16(w1.x) | ((uint32)f2bf16(w1.y) << 16);
    q.w = (uint32)f2bf16(w1.z) | ((uint32)f2bf16(w1.w) << 16);
    return q;
}

__global__ __launch_bounds__(256) void prep_w_kernel(
    const float* __restrict__ w0, const float* __restrict__ w1,
    const float* __restrict__ wo,
    uint4* __restrict__ t0, uint4* __restrict__ t1, uint4* __restrict__ to_)
{
    const int idx = blockIdx.x * 256 + threadIdx.x;
    if (idx < 4096) {                       // lin0: [k8][j], j<128, k8<32
        const int jj = idx & 127, k8 = idx >> 7;
        t0[idx] = packw(w0 + (size_t)jj * FIN + 8 * k8);
    } else if (idx < 6144) {                // lin1: [k8][j], j<128, k8<16
        const int li = idx - 4096;
        const int jj = li & 127, k8 = li >> 7;
        t1[li] = packw(w1 + (size_t)jj * HD + 8 * k8);
    } else if (idx < 7168) {                // lout: [k8][c], c<64, k8<16
        const int li = idx - 6144;
        const int jj = li & 63, k8 = li >> 6;
        to_[li] = packw(wo + (size_t)jj * HD + 8 * k8);
    }
}

// ---------------------------------------------------------------------------
// MFMA linear + fused attention projections. B-fragments straight from the
// bf16 W table. Block = 4 waves; wave owns 16 rows x 128 cols.
// Output h16s is SLICE-MAJOR: [slice s][node][32 ch], s = ch>>5.
// ---------------------------------------------------------------------------
template<int DIN, bool ABF16>
__global__ __launch_bounds__(256) void linear_mfma_kernel(
    const void* __restrict__ Ain, const uint4* __restrict__ W16,
    const float* __restrict__ bias,
    const float* __restrict__ alw, const float* __restrict__ alb,
    const float* __restrict__ arw, const float* __restrict__ arb,
    ushort_t* __restrict__ h16s, float* __restrict__ al, float* __restrict__ ar)
{
    const int tid  = threadIdx.x;
    const int wid  = tid >> 6;
    const int lane = tid & 63;
    const int mrow = lane & 15;
    const int kq   = lane >> 4;
    const int row  = blockIdx.x * 64 + wid * 16 + mrow;
    const int arow = row < NN ? row : NN - 1;

    float4v acc[8];
#pragma unroll
    for (int t = 0; t < 8; ++t) acc[t] = (float4v){0.f, 0.f, 0.f, 0.f};

    for (int f0 = 0; f0 < DIN; f0 += 32) {
        short8v a;
        if constexpr (ABF16) {
            a = *(const short8v*)((const ushort_t*)Ain + (size_t)arow * DIN + f0 + 8 * kq);
        } else {
            const float* ap = (const float*)Ain + (size_t)arow * DIN + f0 + 8 * kq;
            const float4 a0 = *(const float4*)ap;
            const float4 a1 = *(const float4*)(ap + 4);
            a[0] = (short)f2bf16(a0.x); a[1] = (short)f2bf16(a0.y);
            a[2] = (short)f2bf16(a0.z); a[3] = (short)f2bf16(a0.w);
            a[4] = (short)f2bf16(a1.x); a[5] = (short)f2bf16(a1.y);
            a[6] = (short)f2bf16(a1.z); a[7] = (short)f2bf16(a1.w);
        }
        const int k8 = (f0 >> 3) + kq;
#pragma unroll
        for (int t = 0; t < 8; ++t) {
            const short8v b = ((const short8v*)W16)[(k8 << 7) + 16 * t + mrow];
            acc[t] = __builtin_amdgcn_mfma_f32_16x16x32_bf16(a, b, acc[t], 0, 0, 0);
        }
    }

    // ---- epilogue: bias, slice-major bf16 store, fused al/ar ----
    float pa[4] = {0.f, 0.f, 0.f, 0.f};
    float pr[4] = {0.f, 0.f, 0.f, 0.f};
    float hb[8][4];
#pragma unroll
    for (int t = 0; t < 8; ++t) {
        const float bj = bias[16 * t + mrow];
        const float wl = alw[16 * t + mrow];
        const float wr = arw[16 * t + mrow];
#pragma unroll
        for (int g = 0; g < 4; ++g) {
            const float h = acc[t][g] + bj;
            hb[t][g] = h;
            pa[g] = fmaf(h, wl, pa[g]);
            pr[g] = fmaf(h, wr, pr[g]);
        }
    }
    const int rbase = blockIdx.x * 64 + wid * 16 + 4 * kq;
#pragma unroll
    for (int g = 0; g < 4; ++g) {
        const int orow = rbase + g;
        if (orow < NN) {
#pragma unroll
            for (int t = 0; t < 8; ++t) {
                // channel c = 16t + mrow; slice = t>>1; offset = 16*(t&1)+mrow
                h16s[(size_t)(t >> 1) * (NN * 32) + (size_t)orow * 32 +
                     16 * (t & 1) + mrow] = f2bf16(hb[t][g]);
            }
        }
    }
#pragma unroll
    for (int o = 8; o >= 1; o >>= 1) {
#pragma unroll
        for (int g = 0; g < 4; ++g) {
            pa[g] += __shfl_xor(pa[g], o, 16);
            pr[g] += __shfl_xor(pr[g], o, 16);
        }
    }
    if (mrow == 0) {
#pragma unroll
        for (int g = 0; g < 4; ++g) {
            const int orow = rbase + g;
            if (orow < NN) {
                al[orow] = pa[g] + alb[0];
                ar[orow] = pr[g] + arb[0];
            }
        }
    }
}

// ---------------------------------------------------------------------------
// Pair prep: packed (w_bf16 << 16 | e) per (node, k, j). One wave per node.
// ---------------------------------------------------------------------------
__global__ __launch_bounds__(256) void prep_pairs_kernel(
    const int* __restrict__ ends_l, const float* __restrict__ al,
    const float* __restrict__ ar, const float* __restrict__ att_l,
    uint32* __restrict__ pw)
{
    const int wv   = threadIdx.x >> 6;
    const int lane = threadIdx.x & 63;
    const int node = blockIdx.x * 4 + wv;
    const int k    = lane >> 4;
    const int j    = lane & 15;

    const int e = __builtin_nontemporal_load(ends_l + (size_t)k * NRW + node * RWSS + j);
    float lg = al[node] + ar[e];
    lg = (lg > 0.f) ? lg : 0.2f * lg;
    float m = lg;
#pragma unroll
    for (int o = 8; o >= 1; o >>= 1) m = fmaxf(m, __shfl_xor(m, o, 16));
    const float ex = __expf(lg - m);
    float s = ex;
#pragma unroll
    for (int o = 8; o >= 1; o >>= 1) s += __shfl_xor(s, o, 16);
    const float w = ex / s * att_l[k + 1] * (1.0f / RWSS);
    const uint32 packed = ((uint32)f2bf16(w) << 16) | (uint32)e;   // e < 65536
    __builtin_nontemporal_store(packed, pw + (size_t)node * 64 + lane);
}

// ---------------------------------------------------------------------------
// Aggregation v5: ONE dispatch per layer; slice pinned to an XCD pair via
// bid&7 (each XCD's L2 permanently holds one 3.2 MB channel-slice).
// Block = 256 = 4 waves = 16 nodes. Wave = 4 nodes; lane = g*16 + r*4 + q.
// Inner loop in TWO BATCHES OF 8 in named regs; __launch_bounds__(256,4)
// (<=128 VGPR) so the ~90-VGPR live set does NOT spill (round-9 lesson:
// (256,8)'s 64-VGPR cap spilled 4 uint4/lane -> 0.5 GB scratch traffic).
// ---------------------------------------------------------------------------
__global__ __launch_bounds__(256, 4) void aggr_slice_kernel(
    const ushort_t* __restrict__ h16s, const uint32* __restrict__ pw,
    const float* __restrict__ att_l, ushort_t* __restrict__ agg16)
{
    const int bid = blockIdx.x;
    const int xcd = bid & 7;
    const int s   = xcd >> 1;                       // slice 0..3
    const int ng  = (bid >> 3) + (xcd & 1) * 1563;  // node-group within slice
    if (ng >= 3125) return;                         // block-uniform guard
    const int node0 = ng * 16;

    __shared__ uint32 pair_s[16 * 68];
    const int tid = threadIdx.x;
    // stage 1024 pairs (16 nodes x 64), NT dwordx4, stride-68 LDS rows
    {
        const uint4v p4 = __builtin_nontemporal_load(
            (const uint4v*)(pw + (size_t)node0 * 64) + tid);
        const int nl = tid >> 4;
        const int sm = (4 * tid) & 63;
        *(uint4v*)&pair_s[nl * 68 + sm] = p4;
    }
    __syncthreads();

    const int lane = tid & 63;
    const int w    = tid >> 6;
    const int g    = lane >> 4;
    const int r    = (lane >> 2) & 3;
    const int q    = lane & 3;
    const int nl   = w * 4 + g;
    const uint32 qb = (uint32)(q << 4);
    const char* hbase = (const char*)(h16s + (size_t)s * (NN * 32));
    const uint32* ps = &pair_s[nl * 68 + r];

    float acc[8];
#pragma unroll
    for (int c = 0; c < 8; ++c) acc[c] = 0.f;

#pragma unroll
    for (int half = 0; half < 2; ++half) {
        uint32 wgt[8];
        uint4v vv[8];
#pragma unroll
        for (int i = 0; i < 8; ++i) {
            const uint32 p = ps[4 * (8 * half + i)];   // imm-offset ds_read
            wgt[i] = p & 0xFFFF0000u;
            vv[i]  = *(const uint4v*)(hbase + (((p & 0xFFFFu) << 6) + qb));
        }
#pragma unroll
        for (int i = 0; i < 8; ++i) {
            const float w8 = __uint_as_float(wgt[i]);
            acc[0] = fmaf(bf16lo(vv[i].x), w8, acc[0]);
            acc[1] = fmaf(bf16hi(vv[i].x), w8, acc[1]);
            acc[2] = fmaf(bf16lo(vv[i].y), w8, acc[2]);
            acc[3] = fmaf(bf16hi(vv[i].y), w8, acc[3]);
            acc[4] = fmaf(bf16lo(vv[i].z), w8, acc[4]);
            acc[5] = fmaf(bf16hi(vv[i].z), w8, acc[5]);
            acc[6] = fmaf(bf16lo(vv[i].w), w8, acc[6]);
            acc[7] = fmaf(bf16hi(vv[i].w), w8, acc[7]);
        }
    }

#pragma unroll
    for (int c = 0; c < 8; ++c) {
        acc[c] += __shfl_xor(acc[c], 4, 16);
        acc[c] += __shfl_xor(acc[c], 8, 16);
    }

    if (r == 0) {
        const int node = node0 + nl;
        const uint4v v = *(const uint4v*)(hbase + (((uint32)node << 6) + qb));
        const float a0 = att_l[0];
        acc[0] = fmaf(bf16lo(v.x), a0, acc[0]);
        acc[1] = fmaf(bf16hi(v.x), a0, acc[1]);
        acc[2] = fmaf(bf16lo(v.y), a0, acc[2]);
        acc[3] = fmaf(bf16hi(v.y), a0, acc[3]);
        acc[4] = fmaf(bf16lo(v.z), a0, acc[4]);
        acc[5] = fmaf(bf16hi(v.z), a0, acc[5]);
        acc[6] = fmaf(bf16lo(v.w), a0, acc[6]);
        acc[7] = fmaf(bf16hi(v.w), a0, acc[7]);
        uint4v o;
        o.x = (uint32)f2bf16(acc[0]) | ((uint32)f2bf16(acc[1]) << 16);
        o.y = (uint32)f2bf16(acc[2]) | ((uint32)f2bf16(acc[3]) << 16);
        o.z = (uint32)f2bf16(acc[4]) | ((uint32)f2bf16(acc[5]) << 16);
        o.w = (uint32)f2bf16(acc[6]) | ((uint32)f2bf16(acc[7]) << 16);
        __builtin_nontemporal_store(
            o, (uint4v*)((char*)agg16 + (size_t)node * 256 + s * 64 + qb));
    }
}

// ---------------------------------------------------------------------------
// Output head: MFMA GEMM (h @ lout_w^T + b) + fused log_softmax.
// ---------------------------------------------------------------------------
__global__ __launch_bounds__(256) void out_mfma_kernel(
    const ushort_t* __restrict__ agg16, const uint4* __restrict__ WO16,
    const float* __restrict__ lb, float* __restrict__ outp)
{
    const int tid  = threadIdx.x;
    const int wid  = tid >> 6;
    const int lane = tid & 63;
    const int mrow = lane & 15;
    const int kq   = lane >> 4;
    const int row  = blockIdx.x * 64 + wid * 16 + mrow;
    const int arow = row < NN ? row : NN - 1;

    float4v acc[4];
#pragma unroll
    for (int t = 0; t < 4; ++t) acc[t] = (float4v){0.f, 0.f, 0.f, 0.f};

#pragma unroll
    for (int f0 = 0; f0 < HD; f0 += 32) {
        const short8v a = *(const short8v*)(agg16 + (size_t)arow * HD + f0 + 8 * kq);
        const int k8 = (f0 >> 3) + kq;
#pragma unroll
        for (int t = 0; t < 4; ++t) {
            const short8v b = ((const short8v*)WO16)[(k8 << 6) + 16 * t + mrow];
            acc[t] = __builtin_amdgcn_mfma_f32_16x16x32_bf16(a, b, acc[t], 0, 0, 0);
        }
    }

    float v[4][4];
    float mx[4] = {-1e30f, -1e30f, -1e30f, -1e30f};
#pragma unroll
    for (int t = 0; t < 4; ++t) {
        const float bj = lb[16 * t + mrow];
#pragma unroll
        for (int g = 0; g < 4; ++g) {
            v[t][g] = acc[t][g] + bj;
            mx[g] = fmaxf(mx[g], v[t][g]);
        }
    }
#pragma unroll
    for (int o = 8; o >= 1; o >>= 1)
#pragma unroll
        for (int g = 0; g < 4; ++g) mx[g] = fmaxf(mx[g], __shfl_xor(mx[g], o, 16));
    float sm[4] = {0.f, 0.f, 0.f, 0.f};
#pragma unroll
    for (int t = 0; t < 4; ++t)
#pragma unroll
        for (int g = 0; g < 4; ++g) sm[g] += __expf(v[t][g] - mx[g]);
#pragma unroll
    for (int o = 8; o >= 1; o >>= 1)
#pragma unroll
        for (int g = 0; g < 4; ++g) sm[g] += __shfl_xor(sm[g], o, 16);
    float lgs[4];
#pragma unroll
    for (int g = 0; g < 4; ++g) lgs[g] = __logf(sm[g]);

    const int rbase = blockIdx.x * 64 + wid * 16 + 4 * kq;
#pragma unroll
    for (int g = 0; g < 4; ++g) {
        const int orow = rbase + g;
        if (orow < NN) {
#pragma unroll
            for (int t = 0; t < 4; ++t)
                outp[(size_t)orow * CC + 16 * t + mrow] = v[t][g] - mx[g] - lgs[g];
        }
    }
}

// ---------------------------------------------------------------------------
extern "C" void kernel_launch(void* const* d_in, const int* in_sizes, int n_in,
                              void* d_out, int out_size, void* d_ws, size_t ws_size,
                              hipStream_t stream)
{
    const float* x      = (const float*)d_in[0];
    const int*   ends   = (const int*)  d_in[1];
    const float* lin0_w = (const float*)d_in[2];
    const float* lin0_b = (const float*)d_in[3];
    const float* lin1_w = (const float*)d_in[4];
    const float* lin1_b = (const float*)d_in[5];
    const float* lout_w = (const float*)d_in[6];
    const float* lout_b = (const float*)d_in[7];
    const float* attl_w = (const float*)d_in[8];
    const float* attl_b = (const float*)d_in[9];
    const float* attr_w = (const float*)d_in[10];
    const float* attr_b = (const float*)d_in[11];
    const float* att    = (const float*)d_in[12];
    float* outp = (float*)d_out;

    // workspace layout (~39 MB)
    ushort_t* h16s  = (ushort_t*)d_ws;                    // slice-major table, 12.8MB
    ushort_t* agg16 = h16s + (size_t)NN * HD;             // row-major agg, 12.8MB
    float*    albuf = (float*)(agg16 + (size_t)NN * HD);  // 50000
    float*    arbuf = albuf + NN;                         // 50000
    uint32*   pw    = (uint32*)(arbuf + NN);              // 3.2M packed pairs, 12.8MB
    uint4*    t0    = (uint4*)(pw + (size_t)KNRW);        // 4096 chunks
    uint4*    t1    = t0 + 4096;                          // 2048 chunks
    uint4*    to_   = t1 + 2048;                          // 1024 chunks

    const int lin_grid  = (NN + 63) / 64;   // 782
    const int nb4       = NN / 4;           // 12500, exact
    const int aggr_grid = 8 * 1563;         // 12504 (xcd-pinned slices)

    prep_w_kernel<<<28, 256, 0, stream>>>(lin0_w, lin1_w, lout_w, t0, t1, to_);

    // ---- layer 0 ----
    linear_mfma_kernel<FIN, false><<<lin_grid, 256, 0, stream>>>(
        x, t0, lin0_b, attl_w, attl_b, attr_w, attr_b, h16s, albuf, arbuf);
    prep_pairs_kernel<<<nb4, 256, 0, stream>>>(ends, albuf, arbuf, att, pw);
    aggr_slice_kernel<<<aggr_grid, 256, 0, stream>>>(h16s, pw, att, agg16);

    // ---- layer 1 ----
    linear_mfma_kernel<HD, true><<<lin_grid, 256, 0, stream>>>(
        agg16, t1, lin1_b, attl_w + HD, attl_b + 1, attr_w + HD, attr_b + 1,
        h16s, albuf, arbuf);
    prep_pairs_kernel<<<nb4, 256, 0, stream>>>(ends + KNRW, albuf, arbuf,
                                               att + (KK + 1), pw);
    aggr_slice_kernel<<<aggr_grid, 256, 0, stream>>>(h16s, pw, att + (KK + 1), agg16);

    // ---- output head ----
    out_mfma_kernel<<<lin_grid, 256, 0, stream>>>(agg16, to_, lout_b, outp);
}

// Round 11
// 166.392 us; speedup vs baseline: 2.3321x; 1.3539x over previous
//
#include <hip/hip_runtime.h>

#define NN   50000
#define FIN  256
#define HD   128
#define CC   64
#define KK   4
#define RWSS 16
#define NRW  (NN*RWSS)          // 800000
#define KNRW (KK*NRW)           // 3200000

typedef unsigned int   uint32;
typedef unsigned short ushort_t;

typedef __attribute__((ext_vector_type(8))) short short8v;   // 8 bf16
typedef __attribute__((ext_vector_type(4))) float float4v;   // MFMA acc
typedef __attribute__((ext_vector_type(4))) uint32 uint4v;   // native 16B vec
typedef __attribute__((ext_vector_type(2))) float float2v;

static __device__ __forceinline__ float bf16lo(uint32 u) {
    return __uint_as_float(u << 16);
}
static __device__ __forceinline__ float bf16hi(uint32 u) {
    return __uint_as_float(u & 0xFFFF0000u);
}
static __device__ __forceinline__ ushort_t f2bf16(float f) {
    uint32 u = __float_as_uint(f);
    uint32 r = u + 0x7FFFu + ((u >> 16) & 1u);   // RNE
    return (ushort_t)(r >> 16);
}

// ---- fp8 e4m3 helpers -----------------------------------------------------
#if __has_builtin(__builtin_amdgcn_cvt_pk_fp8_f32) && __has_builtin(__builtin_amdgcn_cvt_pk_f32_fp8)
#define FP8_HW 1
#define WGT_SCALE 1.0f
static __device__ __forceinline__ uint32 enc_e4m3(float f) {
    return (uint32)__builtin_amdgcn_cvt_pk_fp8_f32(f, f, 0, false) & 0xFFu;
}
#else
#define FP8_HW 0
#define WGT_SCALE 0x1p120f
static __device__ __forceinline__ uint32 enc_e4m3(float f) {
    const uint32 u    = __float_as_uint(f);
    const uint32 sign = (u >> 24) & 0x80u;
    const uint32 au   = u & 0x7FFFFFFFu;
    const uint32 r    = au + 0x7FFFFu + ((au >> 20) & 1u);   // RNE at bit 20
    int v = (int)(r >> 20) - 960;                            // rebias 127->7
    v = v < 0 ? 0 : (v > 127 ? 127 : v);
    return sign | (uint32)v;
}
#endif

// accumulate 4 fp8 (one dword) * w into acc[0..3]
static __device__ __forceinline__ void fma_fp8x4(
    uint32 d, float w, float* acc)
{
#if FP8_HW
    const float2v lo = __builtin_amdgcn_cvt_pk_f32_fp8(d, false);
    const float2v hi = __builtin_amdgcn_cvt_pk_f32_fp8(d, true);
    acc[0] = fmaf(lo.x, w, acc[0]);
    acc[1] = fmaf(lo.y, w, acc[1]);
    acc[2] = fmaf(hi.x, w, acc[2]);
    acc[3] = fmaf(hi.y, w, acc[3]);
#else
    // w already carries the 2^120 rebias
#pragma unroll
    for (int k = 0; k < 4; ++k) {
        const uint32 b = (d >> (8 * k)) & 0xFFu;
        const float  x = __uint_as_float(((b & 0x80u) << 24) | ((b & 0x7Fu) << 20));
        acc[k] = fmaf(x, w, acc[k]);
    }
#endif
}

// ---------------------------------------------------------------------------
// One-time weight conversion fp32 -> bf16 k-major 16B chunks [k8][col].
// ---------------------------------------------------------------------------
static __device__ __forceinline__ uint4 packw(const float* p) {
    const float4 w0 = *(const float4*)p;
    const float4 w1 = *(const float4*)(p + 4);
    uint4 q;
    q.x = (uint32)f2bf16(w0.x) | ((uint32)f2bf16(w0.y) << 16);
    q.y = (uint32)f2bf16(w0.z) | ((uint32)f2bf16(w0.w) << 16);
    q.z = (uint32)f2bf16(w1.x) | ((uint32)f2bf16(w1.y) << 16);
    q.w = (uint32)f2bf16(w1.z) | ((uint32)f2bf16(w1.w) << 16);
    return q;
}

__global__ __launch_bounds__(256) void prep_w_kernel(
    const float* __restrict__ w0, const float* __restrict__ w1,
    const float* __restrict__ wo,
    uint4* __restrict__ t0, uint4* __restrict__ t1, uint4* __restrict__ to_)
{
    const int idx = blockIdx.x * 256 + threadIdx.x;
    if (idx < 4096) {                       // lin0: [k8][j], j<128, k8<32
        const int jj = idx & 127, k8 = idx >> 7;
        t0[idx] = packw(w0 + (size_t)jj * FIN + 8 * k8);
    } else if (idx < 6144) {                // lin1: [k8][j], j<128, k8<16
        const int li = idx - 4096;
        const int jj = li & 127, k8 = li >> 7;
        t1[li] = packw(w1 + (size_t)jj * HD + 8 * k8);
    } else if (idx < 7168) {                // lout: [k8][c], c<64, k8<16
        const int li = idx - 6144;
        const int jj = li & 63, k8 = li >> 6;
        to_[li] = packw(wo + (size_t)jj * HD + 8 * k8);
    }
}

// ---------------------------------------------------------------------------
// MFMA linear + fused attention projections. B-fragments straight from the
// bf16 W table. Block = 4 waves; wave owns 16 rows x 128 cols.
// Output h8s is fp8 e4m3, SLICE-MAJOR: [slice s][node][64 ch], s = ch>>6.
// ---------------------------------------------------------------------------
template<int DIN, bool ABF16>
__global__ __launch_bounds__(256) void linear_mfma_kernel(
    const void* __restrict__ Ain, const uint4* __restrict__ W16,
    const float* __restrict__ bias,
    const float* __restrict__ alw, const float* __restrict__ alb,
    const float* __restrict__ arw, const float* __restrict__ arb,
    unsigned char* __restrict__ h8s, float* __restrict__ al, float* __restrict__ ar)
{
    const int tid  = threadIdx.x;
    const int wid  = tid >> 6;
    const int lane = tid & 63;
    const int mrow = lane & 15;
    const int kq   = lane >> 4;
    const int row  = blockIdx.x * 64 + wid * 16 + mrow;
    const int arow = row < NN ? row : NN - 1;

    float4v acc[8];
#pragma unroll
    for (int t = 0; t < 8; ++t) acc[t] = (float4v){0.f, 0.f, 0.f, 0.f};

    for (int f0 = 0; f0 < DIN; f0 += 32) {
        short8v a;
        if constexpr (ABF16) {
            a = *(const short8v*)((const ushort_t*)Ain + (size_t)arow * DIN + f0 + 8 * kq);
        } else {
            const float* ap = (const float*)Ain + (size_t)arow * DIN + f0 + 8 * kq;
            const float4 a0 = *(const float4*)ap;
            const float4 a1 = *(const float4*)(ap + 4);
            a[0] = (short)f2bf16(a0.x); a[1] = (short)f2bf16(a0.y);
            a[2] = (short)f2bf16(a0.z); a[3] = (short)f2bf16(a0.w);
            a[4] = (short)f2bf16(a1.x); a[5] = (short)f2bf16(a1.y);
            a[6] = (short)f2bf16(a1.z); a[7] = (short)f2bf16(a1.w);
        }
        const int k8 = (f0 >> 3) + kq;
#pragma unroll
        for (int t = 0; t < 8; ++t) {
            const short8v b = ((const short8v*)W16)[(k8 << 7) + 16 * t + mrow];
            acc[t] = __builtin_amdgcn_mfma_f32_16x16x32_bf16(a, b, acc[t], 0, 0, 0);
        }
    }

    // ---- epilogue: bias, fp8 slice-major store, fused al/ar ----
    float pa[4] = {0.f, 0.f, 0.f, 0.f};
    float pr[4] = {0.f, 0.f, 0.f, 0.f};
    float hb[8][4];
#pragma unroll
    for (int t = 0; t < 8; ++t) {
        const float bj = bias[16 * t + mrow];
        const float wl = alw[16 * t + mrow];
        const float wr = arw[16 * t + mrow];
#pragma unroll
        for (int g = 0; g < 4; ++g) {
            const float h = acc[t][g] + bj;
            hb[t][g] = h;
            pa[g] = fmaf(h, wl, pa[g]);
            pr[g] = fmaf(h, wr, pr[g]);
        }
    }
    const int rbase = blockIdx.x * 64 + wid * 16 + 4 * kq;
#pragma unroll
    for (int g = 0; g < 4; ++g) {
        const int orow = rbase + g;
        if (orow < NN) {
#pragma unroll
            for (int t = 0; t < 8; ++t) {
                // channel c = 16t + mrow; slice = t>>2; in-row byte = 16*(t&3)+mrow
                h8s[(size_t)(t >> 2) * (NN * 64) + (size_t)orow * 64 +
                    16 * (t & 3) + mrow] = (unsigned char)enc_e4m3(hb[t][g]);
            }
        }
    }
#pragma unroll
    for (int o = 8; o >= 1; o >>= 1) {
#pragma unroll
        for (int g = 0; g < 4; ++g) {
            pa[g] += __shfl_xor(pa[g], o, 16);
            pr[g] += __shfl_xor(pr[g], o, 16);
        }
    }
    if (mrow == 0) {
#pragma unroll
        for (int g = 0; g < 4; ++g) {
            const int orow = rbase + g;
            if (orow < NN) {
                al[orow] = pa[g] + alb[0];
                ar[orow] = pr[g] + arb[0];
            }
        }
    }
}

// ---------------------------------------------------------------------------
// Pair prep: packed (w_bf16 << 16 | e) per (node, k, j). One wave per node.
// ---------------------------------------------------------------------------
__global__ __launch_bounds__(256) void prep_pairs_kernel(
    const int* __restrict__ ends_l, const float* __restrict__ al,
    const float* __restrict__ ar, const float* __restrict__ att_l,
    uint32* __restrict__ pw)
{
    const int wv   = threadIdx.x >> 6;
    const int lane = threadIdx.x & 63;
    const int node = blockIdx.x * 4 + wv;
    const int k    = lane >> 4;
    const int j    = lane & 15;

    const int e = __builtin_nontemporal_load(ends_l + (size_t)k * NRW + node * RWSS + j);
    float lg = al[node] + ar[e];
    lg = (lg > 0.f) ? lg : 0.2f * lg;
    float m = lg;
#pragma unroll
    for (int o = 8; o >= 1; o >>= 1) m = fmaxf(m, __shfl_xor(m, o, 16));
    const float ex = __expf(lg - m);
    float s = ex;
#pragma unroll
    for (int o = 8; o >= 1; o >>= 1) s += __shfl_xor(s, o, 16);
    const float w = ex / s * att_l[k + 1] * (1.0f / RWSS);
    const uint32 packed = ((uint32)f2bf16(w) << 16) | (uint32)e;   // e < 65536
    __builtin_nontemporal_store(packed, pw + (size_t)node * 64 + lane);
}

// ---------------------------------------------------------------------------
// Aggregation v6 (fp8): ONE dispatch per layer. 2 slices x 64 ch (row=64B,
// slice table 3.2MB -> L2-resident); slice pinned to an XCD QUAD via bid&7.
// Block = 256 = 4 waves = 16 nodes. Wave = 4 nodes; lane = g*16 + r*4 + q.
// Per iter: lane gathers dwordx4 = 16 fp8 channels of row 4i+r of node g.
// Lines per (node,sample) = 2 vs bf16's 4  -> halves the 64B-line count,
// which rounds 8/10 showed is the wall (~0.7 lines/cyc/CU regardless of
// occupancy/batching). Two batches of 8 in named regs; (256,4) = no spill.
// ---------------------------------------------------------------------------
__global__ __launch_bounds__(256, 4) void aggr_slice_kernel(
    const unsigned char* __restrict__ h8s, const uint32* __restrict__ pw,
    const float* __restrict__ att_l, ushort_t* __restrict__ agg16)
{
    const int bid = blockIdx.x;
    const int xcd = bid & 7;
    const int s   = xcd >> 2;                       // slice 0..1
    const int ng  = (bid >> 3) + (xcd & 3) * 782;   // node-group within slice
    if (ng >= 3125) return;                         // block-uniform guard
    const int node0 = ng * 16;

    __shared__ uint32 pair_s[16 * 68];
    const int tid = threadIdx.x;
    // stage 1024 pairs (16 nodes x 64), NT dwordx4, stride-68 LDS rows
    {
        const uint4v p4 = __builtin_nontemporal_load(
            (const uint4v*)(pw + (size_t)node0 * 64) + tid);
        const int nl = tid >> 4;
        const int sm = (4 * tid) & 63;
        *(uint4v*)&pair_s[nl * 68 + sm] = p4;
    }
    __syncthreads();

    const int lane = tid & 63;
    const int w    = tid >> 6;
    const int g    = lane >> 4;
    const int r    = (lane >> 2) & 3;
    const int q    = lane & 3;
    const int nl   = w * 4 + g;
    const uint32 qb = (uint32)(q << 4);          // 16B chunk offset in 64B row
    const unsigned char* hbase = h8s + (size_t)s * (NN * 64);
    const uint32* ps = &pair_s[nl * 68 + r];

    float acc[16];
#pragma unroll
    for (int c = 0; c < 16; ++c) acc[c] = 0.f;

#pragma unroll
    for (int half = 0; half < 2; ++half) {
        uint32 wgt[8];
        uint4v vv[8];
#pragma unroll
        for (int i = 0; i < 8; ++i) {
            const uint32 p = ps[4 * (8 * half + i)];   // imm-offset ds_read
            wgt[i] = p & 0xFFFF0000u;
            vv[i]  = *(const uint4v*)(hbase + (((p & 0xFFFFu) << 6) + qb));
        }
#pragma unroll
        for (int i = 0; i < 8; ++i) {
            const float w8 = __uint_as_float(wgt[i]) * WGT_SCALE;
            fma_fp8x4(vv[i].x, w8, acc + 0);
            fma_fp8x4(vv[i].y, w8, acc + 4);
            fma_fp8x4(vv[i].z, w8, acc + 8);
            fma_fp8x4(vv[i].w, w8, acc + 12);
        }
    }

#pragma unroll
    for (int c = 0; c < 16; ++c) {
        acc[c] += __shfl_xor(acc[c], 4, 16);
        acc[c] += __shfl_xor(acc[c], 8, 16);
    }

    if (r == 0) {
        const int node = node0 + nl;
        const uint4v v = *(const uint4v*)(hbase + (((uint32)node << 6) + qb));
        const float a0 = att_l[0] * WGT_SCALE;
        fma_fp8x4(v.x, a0, acc + 0);
        fma_fp8x4(v.y, a0, acc + 4);
        fma_fp8x4(v.z, a0, acc + 8);
        fma_fp8x4(v.w, a0, acc + 12);
        uint4v o1, o2;
        o1.x = (uint32)f2bf16(acc[0])  | ((uint32)f2bf16(acc[1])  << 16);
        o1.y = (uint32)f2bf16(acc[2])  | ((uint32)f2bf16(acc[3])  << 16);
        o1.z = (uint32)f2bf16(acc[4])  | ((uint32)f2bf16(acc[5])  << 16);
        o1.w = (uint32)f2bf16(acc[6])  | ((uint32)f2bf16(acc[7])  << 16);
        o2.x = (uint32)f2bf16(acc[8])  | ((uint32)f2bf16(acc[9])  << 16);
        o2.y = (uint32)f2bf16(acc[10]) | ((uint32)f2bf16(acc[11]) << 16);
        o2.z = (uint32)f2bf16(acc[12]) | ((uint32)f2bf16(acc[13]) << 16);
        o2.w = (uint32)f2bf16(acc[14]) | ((uint32)f2bf16(acc[15]) << 16);
        char* dst = (char*)agg16 + (size_t)node * 256 + s * 128 + q * 32;
        __builtin_nontemporal_store(o1, (uint4v*)dst);
        __builtin_nontemporal_store(o2, (uint4v*)(dst + 16));
    }
}

// ---------------------------------------------------------------------------
// Output head: MFMA GEMM (h @ lout_w^T + b) + fused log_softmax.
// ---------------------------------------------------------------------------
__global__ __launch_bounds__(256) void out_mfma_kernel(
    const ushort_t* __restrict__ agg16, const uint4* __restrict__ WO16,
    const float* __restrict__ lb, float* __restrict__ outp)
{
    const int tid  = threadIdx.x;
    const int wid  = tid >> 6;
    const int lane = tid & 63;
    const int mrow = lane & 15;
    const int kq   = lane >> 4;
    const int row  = blockIdx.x * 64 + wid * 16 + mrow;
    const int arow = row < NN ? row : NN - 1;

    float4v acc[4];
#pragma unroll
    for (int t = 0; t < 4; ++t) acc[t] = (float4v){0.f, 0.f, 0.f, 0.f};

#pragma unroll
    for (int f0 = 0; f0 < HD; f0 += 32) {
        const short8v a = *(const short8v*)(agg16 + (size_t)arow * HD + f0 + 8 * kq);
        const int k8 = (f0 >> 3) + kq;
#pragma unroll
        for (int t = 0; t < 4; ++t) {
            const short8v b = ((const short8v*)WO16)[(k8 << 6) + 16 * t + mrow];
            acc[t] = __builtin_amdgcn_mfma_f32_16x16x32_bf16(a, b, acc[t], 0, 0, 0);
        }
    }

    float v[4][4];
    float mx[4] = {-1e30f, -1e30f, -1e30f, -1e30f};
#pragma unroll
    for (int t = 0; t < 4; ++t) {
        const float bj = lb[16 * t + mrow];
#pragma unroll
        for (int g = 0; g < 4; ++g) {
            v[t][g] = acc[t][g] + bj;
            mx[g] = fmaxf(mx[g], v[t][g]);
        }
    }
#pragma unroll
    for (int o = 8; o >= 1; o >>= 1)
#pragma unroll
        for (int g = 0; g < 4; ++g) mx[g] = fmaxf(mx[g], __shfl_xor(mx[g], o, 16));
    float sm[4] = {0.f, 0.f, 0.f, 0.f};
#pragma unroll
    for (int t = 0; t < 4; ++t)
#pragma unroll
        for (int g = 0; g < 4; ++g) sm[g] += __expf(v[t][g] - mx[g]);
#pragma unroll
    for (int o = 8; o >= 1; o >>= 1)
#pragma unroll
        for (int g = 0; g < 4; ++g) sm[g] += __shfl_xor(sm[g], o, 16);
    float lgs[4];
#pragma unroll
    for (int g = 0; g < 4; ++g) lgs[g] = __logf(sm[g]);

    const int rbase = blockIdx.x * 64 + wid * 16 + 4 * kq;
#pragma unroll
    for (int g = 0; g < 4; ++g) {
        const int orow = rbase + g;
        if (orow < NN) {
#pragma unroll
            for (int t = 0; t < 4; ++t)
                outp[(size_t)orow * CC + 16 * t + mrow] = v[t][g] - mx[g] - lgs[g];
        }
    }
}

// ---------------------------------------------------------------------------
extern "C" void kernel_launch(void* const* d_in, const int* in_sizes, int n_in,
                              void* d_out, int out_size, void* d_ws, size_t ws_size,
                              hipStream_t stream)
{
    const float* x      = (const float*)d_in[0];
    const int*   ends   = (const int*)  d_in[1];
    const float* lin0_w = (const float*)d_in[2];
    const float* lin0_b = (const float*)d_in[3];
    const float* lin1_w = (const float*)d_in[4];
    const float* lin1_b = (const float*)d_in[5];
    const float* lout_w = (const float*)d_in[6];
    const float* lout_b = (const float*)d_in[7];
    const float* attl_w = (const float*)d_in[8];
    const float* attl_b = (const float*)d_in[9];
    const float* attr_w = (const float*)d_in[10];
    const float* attr_b = (const float*)d_in[11];
    const float* att    = (const float*)d_in[12];
    float* outp = (float*)d_out;

    // workspace layout (~33 MB)
    unsigned char* h8s   = (unsigned char*)d_ws;            // fp8 table, 6.4MB
    ushort_t*      agg16 = (ushort_t*)(h8s + (size_t)2 * NN * 64);  // 12.8MB
    float*         albuf = (float*)(agg16 + (size_t)NN * HD);       // 50000
    float*         arbuf = albuf + NN;                              // 50000
    uint32*        pw    = (uint32*)(arbuf + NN);           // 3.2M pairs, 12.8MB
    uint4*         t0    = (uint4*)(pw + (size_t)KNRW);     // 4096 chunks
    uint4*         t1    = t0 + 4096;                       // 2048 chunks
    uint4*         to_   = t1 + 2048;                       // 1024 chunks

    const int lin_grid  = (NN + 63) / 64;   // 782
    const int nb4       = NN / 4;           // 12500, exact
    const int aggr_grid = 8 * 782;          // 6256 (xcd-quad-pinned slices)

    prep_w_kernel<<<28, 256, 0, stream>>>(lin0_w, lin1_w, lout_w, t0, t1, to_);

    // ---- layer 0 ----
    linear_mfma_kernel<FIN, false><<<lin_grid, 256, 0, stream>>>(
        x, t0, lin0_b, attl_w, attl_b, attr_w, attr_b, h8s, albuf, arbuf);
    prep_pairs_kernel<<<nb4, 256, 0, stream>>>(ends, albuf, arbuf, att, pw);
    aggr_slice_kernel<<<aggr_grid, 256, 0, stream>>>(h8s, pw, att, agg16);

    // ---- layer 1 ----
    linear_mfma_kernel<HD, true><<<lin_grid, 256, 0, stream>>>(
        agg16, t1, lin1_b, attl_w + HD, attl_b + 1, attr_w + HD, attr_b + 1,
        h8s, albuf, arbuf);
    prep_pairs_kernel<<<nb4, 256, 0, stream>>>(ends + KNRW, albuf, arbuf,
                                               att + (KK + 1), pw);
    aggr_slice_kernel<<<aggr_grid, 256, 0, stream>>>(h8s, pw, att + (KK + 1), agg16);

    // ---- output head ----
    out_mfma_kernel<<<lin_grid, 256, 0, stream>>>(agg16, to_, lout_b, outp);
}

// Round 12
// 163.936 us; speedup vs baseline: 2.3670x; 1.0150x over previous
//
#include <hip/hip_runtime.h>

#define NN   50000
#define FIN  256
#define HD   128
#define CC   64
#define KK   4
#define RWSS 16
#define NRW  (NN*RWSS)          // 800000
#define KNRW (KK*NRW)           // 3200000

typedef unsigned int   uint32;
typedef unsigned short ushort_t;

typedef __attribute__((ext_vector_type(8))) short short8v;   // 8 bf16
typedef __attribute__((ext_vector_type(4))) float float4v;   // MFMA acc
typedef __attribute__((ext_vector_type(4))) uint32 uint4v;   // native 16B vec
typedef __attribute__((ext_vector_type(2))) float float2v;

static __device__ __forceinline__ float bf16lo(uint32 u) {
    return __uint_as_float(u << 16);
}
static __device__ __forceinline__ float bf16hi(uint32 u) {
    return __uint_as_float(u & 0xFFFF0000u);
}
static __device__ __forceinline__ ushort_t f2bf16(float f) {
    uint32 u = __float_as_uint(f);
    uint32 r = u + 0x7FFFu + ((u >> 16) & 1u);   // RNE
    return (ushort_t)(r >> 16);
}

// ---- fp8 e4m3 helpers -----------------------------------------------------
#if __has_builtin(__builtin_amdgcn_cvt_pk_fp8_f32) && __has_builtin(__builtin_amdgcn_cvt_pk_f32_fp8)
#define FP8_HW 1
#define WGT_SCALE 1.0f
static __device__ __forceinline__ uint32 enc_e4m3(float f) {
    return (uint32)__builtin_amdgcn_cvt_pk_fp8_f32(f, f, 0, false) & 0xFFu;
}
#else
#define FP8_HW 0
#define WGT_SCALE 0x1p120f
static __device__ __forceinline__ uint32 enc_e4m3(float f) {
    const uint32 u    = __float_as_uint(f);
    const uint32 sign = (u >> 24) & 0x80u;
    const uint32 au   = u & 0x7FFFFFFFu;
    const uint32 r    = au + 0x7FFFFu + ((au >> 20) & 1u);   // RNE at bit 20
    int v = (int)(r >> 20) - 960;                            // rebias 127->7
    v = v < 0 ? 0 : (v > 127 ? 127 : v);
    return sign | (uint32)v;
}
#endif

// acc2[0] += cvt(lo(d))*w2 ; acc2[1] += cvt(hi(d))*w2   (packed f32 fma)
static __device__ __forceinline__ void pk_fma_fp8x4(
    uint32 d, float2v w2, float2v* acc2)
{
#if FP8_HW
    const float2v lo = __builtin_amdgcn_cvt_pk_f32_fp8(d, false);
    const float2v hi = __builtin_amdgcn_cvt_pk_f32_fp8(d, true);
    acc2[0] = __builtin_elementwise_fma(lo, w2, acc2[0]);
    acc2[1] = __builtin_elementwise_fma(hi, w2, acc2[1]);
#else
    float2v lo, hi;
    {
        const uint32 b0 = d & 0xFFu, b1 = (d >> 8) & 0xFFu;
        const uint32 b2 = (d >> 16) & 0xFFu, b3 = (d >> 24) & 0xFFu;
        lo.x = __uint_as_float(((b0 & 0x80u) << 24) | ((b0 & 0x7Fu) << 20));
        lo.y = __uint_as_float(((b1 & 0x80u) << 24) | ((b1 & 0x7Fu) << 20));
        hi.x = __uint_as_float(((b2 & 0x80u) << 24) | ((b2 & 0x7Fu) << 20));
        hi.y = __uint_as_float(((b3 & 0x80u) << 24) | ((b3 & 0x7Fu) << 20));
    }
    acc2[0] = __builtin_elementwise_fma(lo, w2, acc2[0]);
    acc2[1] = __builtin_elementwise_fma(hi, w2, acc2[1]);
#endif
}

// ---------------------------------------------------------------------------
// One-time weight conversion fp32 -> bf16 k-major 16B chunks [k8][col].
// ---------------------------------------------------------------------------
static __device__ __forceinline__ uint4 packw(const float* p) {
    const float4 w0 = *(const float4*)p;
    const float4 w1 = *(const float4*)(p + 4);
    uint4 q;
    q.x = (uint32)f2bf16(w0.x) | ((uint32)f2bf16(w0.y) << 16);
    q.y = (uint32)f2bf16(w0.z) | ((uint32)f2bf16(w0.w) << 16);
    q.z = (uint32)f2bf16(w1.x) | ((uint32)f2bf16(w1.y) << 16);
    q.w = (uint32)f2bf16(w1.z) | ((uint32)f2bf16(w1.w) << 16);
    return q;
}

__global__ __launch_bounds__(256) void prep_w_kernel(
    const float* __restrict__ w0, const float* __restrict__ w1,
    const float* __restrict__ wo,
    uint4* __restrict__ t0, uint4* __restrict__ t1, uint4* __restrict__ to_)
{
    const int idx = blockIdx.x * 256 + threadIdx.x;
    if (idx < 4096) {                       // lin0: [k8][j], j<128, k8<32
        const int jj = idx & 127, k8 = idx >> 7;
        t0[idx] = packw(w0 + (size_t)jj * FIN + 8 * k8);
    } else if (idx < 6144) {                // lin1: [k8][j], j<128, k8<16
        const int li = idx - 4096;
        const int jj = li & 127, k8 = li >> 7;
        t1[li] = packw(w1 + (size_t)jj * HD + 8 * k8);
    } else if (idx < 7168) {                // lout: [k8][c], c<64, k8<16
        const int li = idx - 6144;
        const int jj = li & 63, k8 = li >> 6;
        to_[li] = packw(wo + (size_t)jj * HD + 8 * k8);
    }
}

// ---------------------------------------------------------------------------
// MFMA linear + fused attention projections. B-fragments straight from the
// bf16 W table. Block = 4 waves; wave owns 16 rows x 128 cols.
// Output h8s is fp8 e4m3, SLICE-MAJOR: [slice s][node][64 ch], s = ch>>6.
// ---------------------------------------------------------------------------
template<int DIN, bool ABF16>
__global__ __launch_bounds__(256) void linear_mfma_kernel(
    const void* __restrict__ Ain, const uint4* __restrict__ W16,
    const float* __restrict__ bias,
    const float* __restrict__ alw, const float* __restrict__ alb,
    const float* __restrict__ arw, const float* __restrict__ arb,
    unsigned char* __restrict__ h8s, float* __restrict__ al, float* __restrict__ ar)
{
    const int tid  = threadIdx.x;
    const int wid  = tid >> 6;
    const int lane = tid & 63;
    const int mrow = lane & 15;
    const int kq   = lane >> 4;
    const int row  = blockIdx.x * 64 + wid * 16 + mrow;
    const int arow = row < NN ? row : NN - 1;

    float4v acc[8];
#pragma unroll
    for (int t = 0; t < 8; ++t) acc[t] = (float4v){0.f, 0.f, 0.f, 0.f};

    for (int f0 = 0; f0 < DIN; f0 += 32) {
        short8v a;
        if constexpr (ABF16) {
            a = *(const short8v*)((const ushort_t*)Ain + (size_t)arow * DIN + f0 + 8 * kq);
        } else {
            const float* ap = (const float*)Ain + (size_t)arow * DIN + f0 + 8 * kq;
            const float4 a0 = *(const float4*)ap;
            const float4 a1 = *(const float4*)(ap + 4);
            a[0] = (short)f2bf16(a0.x); a[1] = (short)f2bf16(a0.y);
            a[2] = (short)f2bf16(a0.z); a[3] = (short)f2bf16(a0.w);
            a[4] = (short)f2bf16(a1.x); a[5] = (short)f2bf16(a1.y);
            a[6] = (short)f2bf16(a1.z); a[7] = (short)f2bf16(a1.w);
        }
        const int k8 = (f0 >> 3) + kq;
#pragma unroll
        for (int t = 0; t < 8; ++t) {
            const short8v b = ((const short8v*)W16)[(k8 << 7) + 16 * t + mrow];
            acc[t] = __builtin_amdgcn_mfma_f32_16x16x32_bf16(a, b, acc[t], 0, 0, 0);
        }
    }

    // ---- epilogue: bias, fp8 slice-major store, fused al/ar ----
    float pa[4] = {0.f, 0.f, 0.f, 0.f};
    float pr[4] = {0.f, 0.f, 0.f, 0.f};
    float hb[8][4];
#pragma unroll
    for (int t = 0; t < 8; ++t) {
        const float bj = bias[16 * t + mrow];
        const float wl = alw[16 * t + mrow];
        const float wr = arw[16 * t + mrow];
#pragma unroll
        for (int g = 0; g < 4; ++g) {
            const float h = acc[t][g] + bj;
            hb[t][g] = h;
            pa[g] = fmaf(h, wl, pa[g]);
            pr[g] = fmaf(h, wr, pr[g]);
        }
    }
    const int rbase = blockIdx.x * 64 + wid * 16 + 4 * kq;
#pragma unroll
    for (int g = 0; g < 4; ++g) {
        const int orow = rbase + g;
        if (orow < NN) {
#pragma unroll
            for (int t = 0; t < 8; ++t) {
                // channel c = 16t + mrow; slice = t>>2; in-row byte = 16*(t&3)+mrow
                h8s[(size_t)(t >> 2) * (NN * 64) + (size_t)orow * 64 +
                    16 * (t & 3) + mrow] = (unsigned char)enc_e4m3(hb[t][g]);
            }
        }
    }
#pragma unroll
    for (int o = 8; o >= 1; o >>= 1) {
#pragma unroll
        for (int g = 0; g < 4; ++g) {
            pa[g] += __shfl_xor(pa[g], o, 16);
            pr[g] += __shfl_xor(pr[g], o, 16);
        }
    }
    if (mrow == 0) {
#pragma unroll
        for (int g = 0; g < 4; ++g) {
            const int orow = rbase + g;
            if (orow < NN) {
                al[orow] = pa[g] + alb[0];
                ar[orow] = pr[g] + arb[0];
            }
        }
    }
}

// ---------------------------------------------------------------------------
// Pair prep: packed (w_bf16 << 16 | e) per (node, k, j). One wave per node.
// ---------------------------------------------------------------------------
__global__ __launch_bounds__(256) void prep_pairs_kernel(
    const int* __restrict__ ends_l, const float* __restrict__ al,
    const float* __restrict__ ar, const float* __restrict__ att_l,
    uint32* __restrict__ pw)
{
    const int wv   = threadIdx.x >> 6;
    const int lane = threadIdx.x & 63;
    const int node = blockIdx.x * 4 + wv;
    const int k    = lane >> 4;
    const int j    = lane & 15;

    const int e = __builtin_nontemporal_load(ends_l + (size_t)k * NRW + node * RWSS + j);
    float lg = al[node] + ar[e];
    lg = (lg > 0.f) ? lg : 0.2f * lg;
    float m = lg;
#pragma unroll
    for (int o = 8; o >= 1; o >>= 1) m = fmaxf(m, __shfl_xor(m, o, 16));
    const float ex = __expf(lg - m);
    float s = ex;
#pragma unroll
    for (int o = 8; o >= 1; o >>= 1) s += __shfl_xor(s, o, 16);
    const float w = ex / s * att_l[k + 1] * (1.0f / RWSS);
    const uint32 packed = ((uint32)f2bf16(w) << 16) | (uint32)e;   // e < 65536
    __builtin_nontemporal_store(packed, pw + (size_t)node * 64 + lane);
}

// ---------------------------------------------------------------------------
// Aggregation v7 (fp8, 16-deep MLP, packed fma): ONE dispatch per layer.
// 2 slices x 64 ch (row = 64B line; 3.2MB slice table L2-resident, pinned to
// an XCD quad via bid&7). Block = 256 = 4 waves = 16 nodes; wave = 4 nodes,
// lane = g*16 + r*4 + q. ALL 16 dwordx4 gathers issued into named registers
// (~110 VGPR, fits (256,4)'s 128 cap - r9's spill was the 64 cap), then
// consumed with v_cvt_pk_f32_fp8 + v_pk_fma_f32 (4 VALU / 4 channels).
// ---------------------------------------------------------------------------
__global__ __launch_bounds__(256, 4) void aggr_slice_kernel(
    const unsigned char* __restrict__ h8s, const uint32* __restrict__ pw,
    const float* __restrict__ att_l, ushort_t* __restrict__ agg16)
{
    const int bid = blockIdx.x;
    const int xcd = bid & 7;
    const int s   = xcd >> 2;                       // slice 0..1
    const int ng  = (bid >> 3) + (xcd & 3) * 782;   // node-group within slice
    if (ng >= 3125) return;                         // block-uniform guard
    const int node0 = ng * 16;

    __shared__ uint32 pair_s[16 * 68];
    const int tid = threadIdx.x;
    // stage 1024 pairs (16 nodes x 64), NT dwordx4, stride-68 LDS rows
    {
        const uint4v p4 = __builtin_nontemporal_load(
            (const uint4v*)(pw + (size_t)node0 * 64) + tid);
        const int nl = tid >> 4;
        const int sm = (4 * tid) & 63;
        *(uint4v*)&pair_s[nl * 68 + sm] = p4;
    }
    __syncthreads();

    const int lane = tid & 63;
    const int w    = tid >> 6;
    const int g    = lane >> 4;
    const int r    = (lane >> 2) & 3;
    const int q    = lane & 3;
    const int nl   = w * 4 + g;
    const uint32 qb = (uint32)(q << 4);          // 16B chunk offset in 64B row
    const unsigned char* hbase = h8s + (size_t)s * (NN * 64);
    const uint32* ps = &pair_s[nl * 68 + r];

    float2v acc2[8];
#pragma unroll
    for (int c = 0; c < 8; ++c) acc2[c] = (float2v){0.f, 0.f};

    // issue ALL 16 gathers (named regs, static indices)
    uint32 pr16[16];
    uint4v vv[16];
#pragma unroll
    for (int i = 0; i < 16; ++i) {
        pr16[i] = ps[4 * i];                       // imm-offset ds_read
        vv[i]   = *(const uint4v*)(hbase + (((pr16[i] & 0xFFFFu) << 6) + qb));
    }
#pragma unroll
    for (int i = 0; i < 16; ++i) {
        const float wf = __uint_as_float(pr16[i] & 0xFFFF0000u) * WGT_SCALE;
        const float2v w2 = {wf, wf};
        pk_fma_fp8x4(vv[i].x, w2, acc2 + 0);
        pk_fma_fp8x4(vv[i].y, w2, acc2 + 2);
        pk_fma_fp8x4(vv[i].z, w2, acc2 + 4);
        pk_fma_fp8x4(vv[i].w, w2, acc2 + 6);
    }

#pragma unroll
    for (int c = 0; c < 8; ++c) {
        acc2[c].x += __shfl_xor(acc2[c].x, 4, 16);
        acc2[c].y += __shfl_xor(acc2[c].y, 4, 16);
        acc2[c].x += __shfl_xor(acc2[c].x, 8, 16);
        acc2[c].y += __shfl_xor(acc2[c].y, 8, 16);
    }

    if (r == 0) {
        const int node = node0 + nl;
        const uint4v v = *(const uint4v*)(hbase + (((uint32)node << 6) + qb));
        const float a0 = att_l[0] * WGT_SCALE;
        const float2v a2 = {a0, a0};
        pk_fma_fp8x4(v.x, a2, acc2 + 0);
        pk_fma_fp8x4(v.y, a2, acc2 + 2);
        pk_fma_fp8x4(v.z, a2, acc2 + 4);
        pk_fma_fp8x4(v.w, a2, acc2 + 6);
        uint4v o1, o2;
        o1.x = (uint32)f2bf16(acc2[0].x) | ((uint32)f2bf16(acc2[0].y) << 16);
        o1.y = (uint32)f2bf16(acc2[1].x) | ((uint32)f2bf16(acc2[1].y) << 16);
        o1.z = (uint32)f2bf16(acc2[2].x) | ((uint32)f2bf16(acc2[2].y) << 16);
        o1.w = (uint32)f2bf16(acc2[3].x) | ((uint32)f2bf16(acc2[3].y) << 16);
        o2.x = (uint32)f2bf16(acc2[4].x) | ((uint32)f2bf16(acc2[4].y) << 16);
        o2.y = (uint32)f2bf16(acc2[5].x) | ((uint32)f2bf16(acc2[5].y) << 16);
        o2.z = (uint32)f2bf16(acc2[6].x) | ((uint32)f2bf16(acc2[6].y) << 16);
        o2.w = (uint32)f2bf16(acc2[7].x) | ((uint32)f2bf16(acc2[7].y) << 16);
        char* dst = (char*)agg16 + (size_t)node * 256 + s * 128 + q * 32;
        __builtin_nontemporal_store(o1, (uint4v*)dst);
        __builtin_nontemporal_store(o2, (uint4v*)(dst + 16));
    }
}

// ---------------------------------------------------------------------------
// Output head: MFMA GEMM (h @ lout_w^T + b) + fused log_softmax.
// ---------------------------------------------------------------------------
__global__ __launch_bounds__(256) void out_mfma_kernel(
    const ushort_t* __restrict__ agg16, const uint4* __restrict__ WO16,
    const float* __restrict__ lb, float* __restrict__ outp)
{
    const int tid  = threadIdx.x;
    const int wid  = tid >> 6;
    const int lane = tid & 63;
    const int mrow = lane & 15;
    const int kq   = lane >> 4;
    const int row  = blockIdx.x * 64 + wid * 16 + mrow;
    const int arow = row < NN ? row : NN - 1;

    float4v acc[4];
#pragma unroll
    for (int t = 0; t < 4; ++t) acc[t] = (float4v){0.f, 0.f, 0.f, 0.f};

#pragma unroll
    for (int f0 = 0; f0 < HD; f0 += 32) {
        const short8v a = *(const short8v*)(agg16 + (size_t)arow * HD + f0 + 8 * kq);
        const int k8 = (f0 >> 3) + kq;
#pragma unroll
        for (int t = 0; t < 4; ++t) {
            const short8v b = ((const short8v*)WO16)[(k8 << 6) + 16 * t + mrow];
            acc[t] = __builtin_amdgcn_mfma_f32_16x16x32_bf16(a, b, acc[t], 0, 0, 0);
        }
    }

    float v[4][4];
    float mx[4] = {-1e30f, -1e30f, -1e30f, -1e30f};
#pragma unroll
    for (int t = 0; t < 4; ++t) {
        const float bj = lb[16 * t + mrow];
#pragma unroll
        for (int g = 0; g < 4; ++g) {
            v[t][g] = acc[t][g] + bj;
            mx[g] = fmaxf(mx[g], v[t][g]);
        }
    }
#pragma unroll
    for (int o = 8; o >= 1; o >>= 1)
#pragma unroll
        for (int g = 0; g < 4; ++g) mx[g] = fmaxf(mx[g], __shfl_xor(mx[g], o, 16));
    float sm[4] = {0.f, 0.f, 0.f, 0.f};
#pragma unroll
    for (int t = 0; t < 4; ++t)
#pragma unroll
        for (int g = 0; g < 4; ++g) sm[g] += __expf(v[t][g] - mx[g]);
#pragma unroll
    for (int o = 8; o >= 1; o >>= 1)
#pragma unroll
        for (int g = 0; g < 4; ++g) sm[g] += __shfl_xor(sm[g], o, 16);
    float lgs[4];
#pragma unroll
    for (int g = 0; g < 4; ++g) lgs[g] = __logf(sm[g]);

    const int rbase = blockIdx.x * 64 + wid * 16 + 4 * kq;
#pragma unroll
    for (int g = 0; g < 4; ++g) {
        const int orow = rbase + g;
        if (orow < NN) {
#pragma unroll
            for (int t = 0; t < 4; ++t)
                outp[(size_t)orow * CC + 16 * t + mrow] = v[t][g] - mx[g] - lgs[g];
        }
    }
}

// ---------------------------------------------------------------------------
extern "C" void kernel_launch(void* const* d_in, const int* in_sizes, int n_in,
                              void* d_out, int out_size, void* d_ws, size_t ws_size,
                              hipStream_t stream)
{
    const float* x      = (const float*)d_in[0];
    const int*   ends   = (const int*)  d_in[1];
    const float* lin0_w = (const float*)d_in[2];
    const float* lin0_b = (const float*)d_in[3];
    const float* lin1_w = (const float*)d_in[4];
    const float* lin1_b = (const float*)d_in[5];
    const float* lout_w = (const float*)d_in[6];
    const float* lout_b = (const float*)d_in[7];
    const float* attl_w = (const float*)d_in[8];
    const float* attl_b = (const float*)d_in[9];
    const float* attr_w = (const float*)d_in[10];
    const float* attr_b = (const float*)d_in[11];
    const float* att    = (const float*)d_in[12];
    float* outp = (float*)d_out;

    // workspace layout (~33 MB)
    unsigned char* h8s   = (unsigned char*)d_ws;            // fp8 table, 6.4MB
    ushort_t*      agg16 = (ushort_t*)(h8s + (size_t)2 * NN * 64);  // 12.8MB
    float*         albuf = (float*)(agg16 + (size_t)NN * HD);       // 50000
    float*         arbuf = albuf + NN;                              // 50000
    uint32*        pw    = (uint32*)(arbuf + NN);           // 3.2M pairs, 12.8MB
    uint4*         t0    = (uint4*)(pw + (size_t)KNRW);     // 4096 chunks
    uint4*         t1    = t0 + 4096;                       // 2048 chunks
    uint4*         to_   = t1 + 2048;                       // 1024 chunks

    const int lin_grid  = (NN + 63) / 64;   // 782
    const int nb4       = NN / 4;           // 12500, exact
    const int aggr_grid = 8 * 782;          // 6256 (xcd-quad-pinned slices)

    prep_w_kernel<<<28, 256, 0, stream>>>(lin0_w, lin1_w, lout_w, t0, t1, to_);

    // ---- layer 0 ----
    linear_mfma_kernel<FIN, false><<<lin_grid, 256, 0, stream>>>(
        x, t0, lin0_b, attl_w, attl_b, attr_w, attr_b, h8s, albuf, arbuf);
    prep_pairs_kernel<<<nb4, 256, 0, stream>>>(ends, albuf, arbuf, att, pw);
    aggr_slice_kernel<<<aggr_grid, 256, 0, stream>>>(h8s, pw, att, agg16);

    // ---- layer 1 ----
    linear_mfma_kernel<HD, true><<<lin_grid, 256, 0, stream>>>(
        agg16, t1, lin1_b, attl_w + HD, attl_b + 1, attr_w + HD, attr_b + 1,
        h8s, albuf, arbuf);
    prep_pairs_kernel<<<nb4, 256, 0, stream>>>(ends + KNRW, albuf, arbuf,
                                               att + (KK + 1), pw);
    aggr_slice_kernel<<<aggr_grid, 256, 0, stream>>>(h8s, pw, att + (KK + 1), agg16);

    // ---- output head ----
    out_mfma_kernel<<<lin_grid, 256, 0, stream>>>(agg16, to_, lout_b, outp);
}

// Round 13
// 161.662 us; speedup vs baseline: 2.4003x; 1.0141x over previous
//
#include <hip/hip_runtime.h>

#define NN   50000
#define FIN  256
#define HD   128
#define CC   64
#define KK   4
#define RWSS 16
#define NRW  (NN*RWSS)          // 800000
#define KNRW (KK*NRW)           // 3200000

typedef unsigned int   uint32;
typedef unsigned short ushort_t;

typedef __attribute__((ext_vector_type(8))) short short8v;   // 8 bf16
typedef __attribute__((ext_vector_type(4))) float float4v;   // MFMA acc
typedef __attribute__((ext_vector_type(4))) uint32 uint4v;   // native 16B vec
typedef __attribute__((ext_vector_type(2))) float float2v;

static __device__ __forceinline__ float bf16lo(uint32 u) {
    return __uint_as_float(u << 16);
}
static __device__ __forceinline__ float bf16hi(uint32 u) {
    return __uint_as_float(u & 0xFFFF0000u);
}
static __device__ __forceinline__ ushort_t f2bf16(float f) {
    uint32 u = __float_as_uint(f);
    uint32 r = u + 0x7FFFu + ((u >> 16) & 1u);   // RNE
    return (ushort_t)(r >> 16);
}

// ---- fp8 e4m3 helpers -----------------------------------------------------
#if __has_builtin(__builtin_amdgcn_cvt_pk_fp8_f32) && __has_builtin(__builtin_amdgcn_cvt_pk_f32_fp8)
#define FP8_HW 1
#define WGT_SCALE 1.0f
static __device__ __forceinline__ uint32 enc_e4m3(float f) {
    return (uint32)__builtin_amdgcn_cvt_pk_fp8_f32(f, f, 0, false) & 0xFFu;
}
#else
#define FP8_HW 0
#define WGT_SCALE 0x1p120f
static __device__ __forceinline__ uint32 enc_e4m3(float f) {
    const uint32 u    = __float_as_uint(f);
    const uint32 sign = (u >> 24) & 0x80u;
    const uint32 au   = u & 0x7FFFFFFFu;
    const uint32 r    = au + 0x7FFFFu + ((au >> 20) & 1u);   // RNE at bit 20
    int v = (int)(r >> 20) - 960;                            // rebias 127->7
    v = v < 0 ? 0 : (v > 127 ? 127 : v);
    return sign | (uint32)v;
}
#endif

// acc2[0] += cvt(lo(d))*w2 ; acc2[1] += cvt(hi(d))*w2   (packed f32 fma)
static __device__ __forceinline__ void pk_fma_fp8x4(
    uint32 d, float2v w2, float2v* acc2)
{
#if FP8_HW
    const float2v lo = __builtin_amdgcn_cvt_pk_f32_fp8(d, false);
    const float2v hi = __builtin_amdgcn_cvt_pk_f32_fp8(d, true);
    acc2[0] = __builtin_elementwise_fma(lo, w2, acc2[0]);
    acc2[1] = __builtin_elementwise_fma(hi, w2, acc2[1]);
#else
    float2v lo, hi;
    {
        const uint32 b0 = d & 0xFFu, b1 = (d >> 8) & 0xFFu;
        const uint32 b2 = (d >> 16) & 0xFFu, b3 = (d >> 24) & 0xFFu;
        lo.x = __uint_as_float(((b0 & 0x80u) << 24) | ((b0 & 0x7Fu) << 20));
        lo.y = __uint_as_float(((b1 & 0x80u) << 24) | ((b1 & 0x7Fu) << 20));
        hi.x = __uint_as_float(((b2 & 0x80u) << 24) | ((b2 & 0x7Fu) << 20));
        hi.y = __uint_as_float(((b3 & 0x80u) << 24) | ((b3 & 0x7Fu) << 20));
    }
    acc2[0] = __builtin_elementwise_fma(lo, w2, acc2[0]);
    acc2[1] = __builtin_elementwise_fma(hi, w2, acc2[1]);
#endif
}

// ---------------------------------------------------------------------------
// One-time weight conversion fp32 -> bf16 k-major 16B chunks [k8][col].
// ---------------------------------------------------------------------------
static __device__ __forceinline__ uint4 packw(const float* p) {
    const float4 w0 = *(const float4*)p;
    const float4 w1 = *(const float4*)(p + 4);
    uint4 q;
    q.x = (uint32)f2bf16(w0.x) | ((uint32)f2bf16(w0.y) << 16);
    q.y = (uint32)f2bf16(w0.z) | ((uint32)f2bf16(w0.w) << 16);
    q.z = (uint32)f2bf16(w1.x) | ((uint32)f2bf16(w1.y) << 16);
    q.w = (uint32)f2bf16(w1.z) | ((uint32)f2bf16(w1.w) << 16);
    return q;
}

__global__ __launch_bounds__(256) void prep_w_kernel(
    const float* __restrict__ w0, const float* __restrict__ w1,
    const float* __restrict__ wo,
    uint4* __restrict__ t0, uint4* __restrict__ t1, uint4* __restrict__ to_)
{
    const int idx = blockIdx.x * 256 + threadIdx.x;
    if (idx < 4096) {                       // lin0: [k8][j], j<128, k8<32
        const int jj = idx & 127, k8 = idx >> 7;
        t0[idx] = packw(w0 + (size_t)jj * FIN + 8 * k8);
    } else if (idx < 6144) {                // lin1: [k8][j], j<128, k8<16
        const int li = idx - 4096;
        const int jj = li & 127, k8 = li >> 7;
        t1[li] = packw(w1 + (size_t)jj * HD + 8 * k8);
    } else if (idx < 7168) {                // lout: [k8][c], c<64, k8<16
        const int li = idx - 6144;
        const int jj = li & 63, k8 = li >> 6;
        to_[li] = packw(wo + (size_t)jj * HD + 8 * k8);
    }
}

// ---------------------------------------------------------------------------
// MFMA linear + fused attention projections. B-fragments straight from the
// bf16 W table. Block = 4 waves; wave owns 16 rows x 128 cols.
// Output h8s is fp8 e4m3, SLICE-MAJOR: [slice s][node][64 ch], s = ch>>6.
// ---------------------------------------------------------------------------
template<int DIN, bool ABF16>
__global__ __launch_bounds__(256) void linear_mfma_kernel(
    const void* __restrict__ Ain, const uint4* __restrict__ W16,
    const float* __restrict__ bias,
    const float* __restrict__ alw, const float* __restrict__ alb,
    const float* __restrict__ arw, const float* __restrict__ arb,
    unsigned char* __restrict__ h8s, float* __restrict__ al, float* __restrict__ ar)
{
    const int tid  = threadIdx.x;
    const int wid  = tid >> 6;
    const int lane = tid & 63;
    const int mrow = lane & 15;
    const int kq   = lane >> 4;
    const int row  = blockIdx.x * 64 + wid * 16 + mrow;
    const int arow = row < NN ? row : NN - 1;

    float4v acc[8];
#pragma unroll
    for (int t = 0; t < 8; ++t) acc[t] = (float4v){0.f, 0.f, 0.f, 0.f};

    for (int f0 = 0; f0 < DIN; f0 += 32) {
        short8v a;
        if constexpr (ABF16) {
            a = *(const short8v*)((const ushort_t*)Ain + (size_t)arow * DIN + f0 + 8 * kq);
        } else {
            const float* ap = (const float*)Ain + (size_t)arow * DIN + f0 + 8 * kq;
            const float4 a0 = *(const float4*)ap;
            const float4 a1 = *(const float4*)(ap + 4);
            a[0] = (short)f2bf16(a0.x); a[1] = (short)f2bf16(a0.y);
            a[2] = (short)f2bf16(a0.z); a[3] = (short)f2bf16(a0.w);
            a[4] = (short)f2bf16(a1.x); a[5] = (short)f2bf16(a1.y);
            a[6] = (short)f2bf16(a1.z); a[7] = (short)f2bf16(a1.w);
        }
        const int k8 = (f0 >> 3) + kq;
#pragma unroll
        for (int t = 0; t < 8; ++t) {
            const short8v b = ((const short8v*)W16)[(k8 << 7) + 16 * t + mrow];
            acc[t] = __builtin_amdgcn_mfma_f32_16x16x32_bf16(a, b, acc[t], 0, 0, 0);
        }
    }

    // ---- epilogue: bias, fp8 slice-major store, fused al/ar ----
    float pa[4] = {0.f, 0.f, 0.f, 0.f};
    float pr[4] = {0.f, 0.f, 0.f, 0.f};
    float hb[8][4];
#pragma unroll
    for (int t = 0; t < 8; ++t) {
        const float bj = bias[16 * t + mrow];
        const float wl = alw[16 * t + mrow];
        const float wr = arw[16 * t + mrow];
#pragma unroll
        for (int g = 0; g < 4; ++g) {
            const float h = acc[t][g] + bj;
            hb[t][g] = h;
            pa[g] = fmaf(h, wl, pa[g]);
            pr[g] = fmaf(h, wr, pr[g]);
        }
    }
    const int rbase = blockIdx.x * 64 + wid * 16 + 4 * kq;
#pragma unroll
    for (int g = 0; g < 4; ++g) {
        const int orow = rbase + g;
        if (orow < NN) {
#pragma unroll
            for (int t = 0; t < 8; ++t) {
                // channel c = 16t + mrow; slice = t>>2; in-row byte = 16*(t&3)+mrow
                h8s[(size_t)(t >> 2) * (NN * 64) + (size_t)orow * 64 +
                    16 * (t & 3) + mrow] = (unsigned char)enc_e4m3(hb[t][g]);
            }
        }
    }
#pragma unroll
    for (int o = 8; o >= 1; o >>= 1) {
#pragma unroll
        for (int g = 0; g < 4; ++g) {
            pa[g] += __shfl_xor(pa[g], o, 16);
            pr[g] += __shfl_xor(pr[g], o, 16);
        }
    }
    if (mrow == 0) {
#pragma unroll
        for (int g = 0; g < 4; ++g) {
            const int orow = rbase + g;
            if (orow < NN) {
                al[orow] = pa[g] + alb[0];
                ar[orow] = pr[g] + arb[0];
            }
        }
    }
}

// ---------------------------------------------------------------------------
// Pair prep: packed (w_bf16 << 16 | e) per (node, k, j). One wave per node.
// ---------------------------------------------------------------------------
__global__ __launch_bounds__(256) void prep_pairs_kernel(
    const int* __restrict__ ends_l, const float* __restrict__ al,
    const float* __restrict__ ar, const float* __restrict__ att_l,
    uint32* __restrict__ pw)
{
    const int wv   = threadIdx.x >> 6;
    const int lane = threadIdx.x & 63;
    const int node = blockIdx.x * 4 + wv;
    const int k    = lane >> 4;
    const int j    = lane & 15;

    const int e = __builtin_nontemporal_load(ends_l + (size_t)k * NRW + node * RWSS + j);
    float lg = al[node] + ar[e];
    lg = (lg > 0.f) ? lg : 0.2f * lg;
    float m = lg;
#pragma unroll
    for (int o = 8; o >= 1; o >>= 1) m = fmaxf(m, __shfl_xor(m, o, 16));
    const float ex = __expf(lg - m);
    float s = ex;
#pragma unroll
    for (int o = 8; o >= 1; o >>= 1) s += __shfl_xor(s, o, 16);
    const float w = ex / s * att_l[k + 1] * (1.0f / RWSS);
    const uint32 packed = ((uint32)f2bf16(w) << 16) | (uint32)e;   // e < 65536
    __builtin_nontemporal_store(packed, pw + (size_t)node * 64 + lane);
}

// ---------------------------------------------------------------------------
// Aggregation v8: v7 + sched_barrier(0) between the 16-load issue loop and
// the consume loop. Round-12 lesson: without the pin, the compiler collapses
// the batch back to ~4 in-flight loads (VGPR=36); the pin forces all 16
// global_load_dwordx4 to issue first (~110 VGPR, fits (256,4)'s 128 cap),
// raising outstanding 64B lines/CU ~4x against the ~400cy L2 latency wall.
// ---------------------------------------------------------------------------
__global__ __launch_bounds__(256, 4) void aggr_slice_kernel(
    const unsigned char* __restrict__ h8s, const uint32* __restrict__ pw,
    const float* __restrict__ att_l, ushort_t* __restrict__ agg16)
{
    const int bid = blockIdx.x;
    const int xcd = bid & 7;
    const int s   = xcd >> 2;                       // slice 0..1
    const int ng  = (bid >> 3) + (xcd & 3) * 782;   // node-group within slice
    if (ng >= 3125) return;                         // block-uniform guard
    const int node0 = ng * 16;

    __shared__ uint32 pair_s[16 * 68];
    const int tid = threadIdx.x;
    // stage 1024 pairs (16 nodes x 64), NT dwordx4, stride-68 LDS rows
    {
        const uint4v p4 = __builtin_nontemporal_load(
            (const uint4v*)(pw + (size_t)node0 * 64) + tid);
        const int nl = tid >> 4;
        const int sm = (4 * tid) & 63;
        *(uint4v*)&pair_s[nl * 68 + sm] = p4;
    }
    __syncthreads();

    const int lane = tid & 63;
    const int w    = tid >> 6;
    const int g    = lane >> 4;
    const int r    = (lane >> 2) & 3;
    const int q    = lane & 3;
    const int nl   = w * 4 + g;
    const uint32 qb = (uint32)(q << 4);          // 16B chunk offset in 64B row
    const unsigned char* hbase = h8s + (size_t)s * (NN * 64);
    const uint32* ps = &pair_s[nl * 68 + r];

    float2v acc2[8];
#pragma unroll
    for (int c = 0; c < 8; ++c) acc2[c] = (float2v){0.f, 0.f};

    // issue ALL 16 gathers (named regs, static indices)
    uint32 pr16[16];
    uint4v vv[16];
#pragma unroll
    for (int i = 0; i < 16; ++i) {
        pr16[i] = ps[4 * i];                       // imm-offset ds_read
        vv[i]   = *(const uint4v*)(hbase + (((pr16[i] & 0xFFFFu) << 6) + qb));
    }
    __builtin_amdgcn_sched_barrier(0);             // pin: loads BEFORE consumes
#pragma unroll
    for (int i = 0; i < 16; ++i) {
        const float wf = __uint_as_float(pr16[i] & 0xFFFF0000u) * WGT_SCALE;
        const float2v w2 = {wf, wf};
        pk_fma_fp8x4(vv[i].x, w2, acc2 + 0);
        pk_fma_fp8x4(vv[i].y, w2, acc2 + 2);
        pk_fma_fp8x4(vv[i].z, w2, acc2 + 4);
        pk_fma_fp8x4(vv[i].w, w2, acc2 + 6);
    }

#pragma unroll
    for (int c = 0; c < 8; ++c) {
        acc2[c].x += __shfl_xor(acc2[c].x, 4, 16);
        acc2[c].y += __shfl_xor(acc2[c].y, 4, 16);
        acc2[c].x += __shfl_xor(acc2[c].x, 8, 16);
        acc2[c].y += __shfl_xor(acc2[c].y, 8, 16);
    }

    if (r == 0) {
        const int node = node0 + nl;
        const uint4v v = *(const uint4v*)(hbase + (((uint32)node << 6) + qb));
        const float a0 = att_l[0] * WGT_SCALE;
        const float2v a2 = {a0, a0};
        pk_fma_fp8x4(v.x, a2, acc2 + 0);
        pk_fma_fp8x4(v.y, a2, acc2 + 2);
        pk_fma_fp8x4(v.z, a2, acc2 + 4);
        pk_fma_fp8x4(v.w, a2, acc2 + 6);
        uint4v o1, o2;
        o1.x = (uint32)f2bf16(acc2[0].x) | ((uint32)f2bf16(acc2[0].y) << 16);
        o1.y = (uint32)f2bf16(acc2[1].x) | ((uint32)f2bf16(acc2[1].y) << 16);
        o1.z = (uint32)f2bf16(acc2[2].x) | ((uint32)f2bf16(acc2[2].y) << 16);
        o1.w = (uint32)f2bf16(acc2[3].x) | ((uint32)f2bf16(acc2[3].y) << 16);
        o2.x = (uint32)f2bf16(acc2[4].x) | ((uint32)f2bf16(acc2[4].y) << 16);
        o2.y = (uint32)f2bf16(acc2[5].x) | ((uint32)f2bf16(acc2[5].y) << 16);
        o2.z = (uint32)f2bf16(acc2[6].x) | ((uint32)f2bf16(acc2[6].y) << 16);
        o2.w = (uint32)f2bf16(acc2[7].x) | ((uint32)f2bf16(acc2[7].y) << 16);
        char* dst = (char*)agg16 + (size_t)node * 256 + s * 128 + q * 32;
        __builtin_nontemporal_store(o1, (uint4v*)dst);
        __builtin_nontemporal_store(o2, (uint4v*)(dst + 16));
    }
}

// ---------------------------------------------------------------------------
// Output head: MFMA GEMM (h @ lout_w^T + b) + fused log_softmax.
// ---------------------------------------------------------------------------
__global__ __launch_bounds__(256) void out_mfma_kernel(
    const ushort_t* __restrict__ agg16, const uint4* __restrict__ WO16,
    const float* __restrict__ lb, float* __restrict__ outp)
{
    const int tid  = threadIdx.x;
    const int wid  = tid >> 6;
    const int lane = tid & 63;
    const int mrow = lane & 15;
    const int kq   = lane >> 4;
    const int row  = blockIdx.x * 64 + wid * 16 + mrow;
    const int arow = row < NN ? row : NN - 1;

    float4v acc[4];
#pragma unroll
    for (int t = 0; t < 4; ++t) acc[t] = (float4v){0.f, 0.f, 0.f, 0.f};

#pragma unroll
    for (int f0 = 0; f0 < HD; f0 += 32) {
        const short8v a = *(const short8v*)(agg16 + (size_t)arow * HD + f0 + 8 * kq);
        const int k8 = (f0 >> 3) + kq;
#pragma unroll
        for (int t = 0; t < 4; ++t) {
            const short8v b = ((const short8v*)WO16)[(k8 << 6) + 16 * t + mrow];
            acc[t] = __builtin_amdgcn_mfma_f32_16x16x32_bf16(a, b, acc[t], 0, 0, 0);
        }
    }

    float v[4][4];
    float mx[4] = {-1e30f, -1e30f, -1e30f, -1e30f};
#pragma unroll
    for (int t = 0; t < 4; ++t) {
        const float bj = lb[16 * t + mrow];
#pragma unroll
        for (int g = 0; g < 4; ++g) {
            v[t][g] = acc[t][g] + bj;
            mx[g] = fmaxf(mx[g], v[t][g]);
        }
    }
#pragma unroll
    for (int o = 8; o >= 1; o >>= 1)
#pragma unroll
        for (int g = 0; g < 4; ++g) mx[g] = fmaxf(mx[g], __shfl_xor(mx[g], o, 16));
    float sm[4] = {0.f, 0.f, 0.f, 0.f};
#pragma unroll
    for (int t = 0; t < 4; ++t)
#pragma unroll
        for (int g = 0; g < 4; ++g) sm[g] += __expf(v[t][g] - mx[g]);
#pragma unroll
    for (int o = 8; o >= 1; o >>= 1)
#pragma unroll
        for (int g = 0; g < 4; ++g) sm[g] += __shfl_xor(sm[g], o, 16);
    float lgs[4];
#pragma unroll
    for (int g = 0; g < 4; ++g) lgs[g] = __logf(sm[g]);

    const int rbase = blockIdx.x * 64 + wid * 16 + 4 * kq;
#pragma unroll
    for (int g = 0; g < 4; ++g) {
        const int orow = rbase + g;
        if (orow < NN) {
#pragma unroll
            for (int t = 0; t < 4; ++t)
                outp[(size_t)orow * CC + 16 * t + mrow] = v[t][g] - mx[g] - lgs[g];
        }
    }
}

// ---------------------------------------------------------------------------
extern "C" void kernel_launch(void* const* d_in, const int* in_sizes, int n_in,
                              void* d_out, int out_size, void* d_ws, size_t ws_size,
                              hipStream_t stream)
{
    const float* x      = (const float*)d_in[0];
    const int*   ends   = (const int*)  d_in[1];
    const float* lin0_w = (const float*)d_in[2];
    const float* lin0_b = (const float*)d_in[3];
    const float* lin1_w = (const float*)d_in[4];
    const float* lin1_b = (const float*)d_in[5];
    const float* lout_w = (const float*)d_in[6];
    const float* lout_b = (const float*)d_in[7];
    const float* attl_w = (const float*)d_in[8];
    const float* attl_b = (const float*)d_in[9];
    const float* attr_w = (const float*)d_in[10];
    const float* attr_b = (const float*)d_in[11];
    const float* att    = (const float*)d_in[12];
    float* outp = (float*)d_out;

    // workspace layout (~33 MB)
    unsigned char* h8s   = (unsigned char*)d_ws;            // fp8 table, 6.4MB
    ushort_t*      agg16 = (ushort_t*)(h8s + (size_t)2 * NN * 64);  // 12.8MB
    float*         albuf = (float*)(agg16 + (size_t)NN * HD);       // 50000
    float*         arbuf = albuf + NN;                              // 50000
    uint32*        pw    = (uint32*)(arbuf + NN);           // 3.2M pairs, 12.8MB
    uint4*         t0    = (uint4*)(pw + (size_t)KNRW);     // 4096 chunks
    uint4*         t1    = t0 + 4096;                       // 2048 chunks
    uint4*         to_   = t1 + 2048;                       // 1024 chunks

    const int lin_grid  = (NN + 63) / 64;   // 782
    const int nb4       = NN / 4;           // 12500, exact
    const int aggr_grid = 8 * 782;          // 6256 (xcd-quad-pinned slices)

    prep_w_kernel<<<28, 256, 0, stream>>>(lin0_w, lin1_w, lout_w, t0, t1, to_);

    // ---- layer 0 ----
    linear_mfma_kernel<FIN, false><<<lin_grid, 256, 0, stream>>>(
        x, t0, lin0_b, attl_w, attl_b, attr_w, attr_b, h8s, albuf, arbuf);
    prep_pairs_kernel<<<nb4, 256, 0, stream>>>(ends, albuf, arbuf, att, pw);
    aggr_slice_kernel<<<aggr_grid, 256, 0, stream>>>(h8s, pw, att, agg16);

    // ---- layer 1 ----
    linear_mfma_kernel<HD, true><<<lin_grid, 256, 0, stream>>>(
        agg16, t1, lin1_b, attl_w + HD, attl_b + 1, attr_w + HD, attr_b + 1,
        h8s, albuf, arbuf);
    prep_pairs_kernel<<<nb4, 256, 0, stream>>>(ends + KNRW, albuf, arbuf,
                                               att + (KK + 1), pw);
    aggr_slice_kernel<<<aggr_grid, 256, 0, stream>>>(h8s, pw, att + (KK + 1), agg16);

    // ---- output head ----
    out_mfma_kernel<<<lin_grid, 256, 0, stream>>>(agg16, to_, lout_b, outp);
}